// Round 1
// baseline (8483.263 us; speedup 1.0000x reference)
//
#include <hip/hip_runtime.h>
#include <math.h>

#define KNN 75
#define NL 8
#define NB 1024
#define NT 50000
#define NCALI 10000
#define NCHUNK 32
#define CHUNK 1563
#define KC 32
#define QT 64
#define TT 128

__device__ __forceinline__ int swz(int c){ return c + ((c>>5)<<2); }

// ---------------- pad copy (zero-fill pad cols every call: ws is poisoned) ----
__global__ void pad_copy_k(const float* __restrict__ in, float* __restrict__ out,
                           int M, int Din, int Dout){
  int idx = blockIdx.x*256 + threadIdx.x;
  if (idx >= M*Dout) return;
  int r = idx / Dout, c = idx - r*Dout;
  out[idx] = (c < Din) ? in[r*Din + c] : 0.f;
}

// ---------------- MLP GEMM: Out[M][128] = relu(A[M][lda] @ W[kreal][128] + b) --
__global__ __launch_bounds__(256) void mlp_gemm_k(
    const float* __restrict__ A, int lda, int kchunks,
    const float* __restrict__ W, int kreal,
    const float* __restrict__ bias,
    float* __restrict__ Out, int M)
{
  __shared__ float As[KC][132];   // [k][row], pad 132 to spread transpose-write banks
  __shared__ float Bs[KC][148];   // [k][col swizzled]
  int tid = threadIdx.x;
  int r0 = (tid>>4)*8, c0 = (tid&15)*8;
  int rowBase = blockIdx.x*128;
  float acc[8][8];
  #pragma unroll
  for (int i=0;i<8;i++)
    #pragma unroll
    for (int j=0;j<8;j++) acc[i][j]=0.f;

  for (int kc=0;kc<kchunks;kc++){
    { int rr = tid>>3, k4=(tid&7)*4;
      #pragma unroll
      for (int i=0;i<4;i++){
        int row = rr + i*32, gr = rowBase + row;
        float4 v = make_float4(0.f,0.f,0.f,0.f);
        if (gr < M) v = *(const float4*)&A[(size_t)gr*lda + kc*KC + k4];
        As[k4+0][row]=v.x; As[k4+1][row]=v.y; As[k4+2][row]=v.z; As[k4+3][row]=v.w;
      }
    }
    { int kk=tid>>5, c4=(tid&31)*4;
      #pragma unroll
      for (int i=0;i<4;i++){
        int k = kk + i*8, gk = kc*KC + k;
        float4 v = make_float4(0.f,0.f,0.f,0.f);
        if (gk < kreal) v = *(const float4*)&W[(size_t)gk*128 + c4];
        *(float4*)&Bs[k][swz(c4)] = v;
      }
    }
    __syncthreads();
    #pragma unroll 4
    for (int k=0;k<KC;k++){
      float4 a0 = *(const float4*)&As[k][r0];
      float4 a1 = *(const float4*)&As[k][r0+4];
      float4 b0 = *(const float4*)&Bs[k][swz(c0)];
      float4 b1 = *(const float4*)&Bs[k][swz(c0+4)];
      float av[8] = {a0.x,a0.y,a0.z,a0.w,a1.x,a1.y,a1.z,a1.w};
      float bv[8] = {b0.x,b0.y,b0.z,b0.w,b1.x,b1.y,b1.z,b1.w};
      #pragma unroll
      for (int i=0;i<8;i++)
        #pragma unroll
        for (int j=0;j<8;j++) acc[i][j] += av[i]*bv[j];
    }
    __syncthreads();
  }
  float bb[8];
  #pragma unroll
  for (int j=0;j<8;j++) bb[j]=bias[c0+j];
  #pragma unroll
  for (int i=0;i<8;i++){
    int gr = rowBase + r0 + i;
    if (gr < M){
      float o[8];
      #pragma unroll
      for (int j=0;j<8;j++){ float v=acc[i][j]+bb[j]; o[j]=v>0.f?v:0.f; }
      float4 o0 = make_float4(o[0],o[1],o[2],o[3]);
      float4 o1 = make_float4(o[4],o[5],o[6],o[7]);
      *(float4*)&Out[(size_t)gr*128 + c0]   = o0;
      *(float4*)&Out[(size_t)gr*128 + c0+4] = o1;
    }
  }
}

// ---------------- last layer: logits[M][8] into stride-32 rows ----------------
__global__ void mlp8_k(const float* __restrict__ A, const float* __restrict__ W4,
                       const float* __restrict__ b4, float* __restrict__ Out, int M){
  __shared__ float Ws[128*8];
  int tid = threadIdx.x;
  for (int i=tid;i<1024;i+=256) Ws[i]=W4[i];
  __syncthreads();
  int r = blockIdx.x*32 + (tid>>3), c = tid&7;
  if (r >= M) return;
  const float* a = &A[(size_t)r*128];
  float acc = b4[c];
  #pragma unroll 16
  for (int k=0;k<128;k++) acc += a[k]*Ws[k*8+c];
  Out[(size_t)r*32 + c] = acc;
}

// ---------------- softmax over 8 logits, zero cols 8..31 ----------------------
__global__ void softmax_k(float* __restrict__ X, int M){
  int r = blockIdx.x*256 + threadIdx.x;
  if (r >= M) return;
  float* p = &X[(size_t)r*32];
  float v[8], m=-1e30f;
  #pragma unroll
  for (int j=0;j<8;j++){ v[j]=p[j]; m = v[j]>m ? v[j] : m; }
  float s=0.f;
  #pragma unroll
  for (int j=0;j<8;j++){ v[j]=__expf(v[j]-m); s+=v[j]; }
  float inv=1.f/s;
  #pragma unroll
  for (int j=0;j<8;j++) p[j]=v[j]*inv;
  #pragma unroll
  for (int j=8;j<32;j++) p[j]=0.f;
}

// ---------------- row squared-norms (one wave per row) ------------------------
__global__ void rownorm_k(const float* __restrict__ X, float* __restrict__ out,
                          int M, int dp){
  int w = threadIdx.x>>6, lane = threadIdx.x&63;
  int row = blockIdx.x*4 + w;
  if (row >= M) return;
  float s=0.f;
  for (int c=lane;c<dp;c+=64){ float v=X[(size_t)row*dp+c]; s+=v*v; }
  #pragma unroll
  for (int off=32;off>0;off>>=1) s += __shfl_down(s, off, 64);
  if (lane==0) out[row]=s;
}

// ---------------- fused distance + per-chunk top-75 ---------------------------
// grid: (16 q-tiles of 64, 32 N-chunks). keys = (d2 bits & ~7) | label.
__global__ __launch_bounds__(256) void dist_topk_k(
    const float* __restrict__ Qm, const float* __restrict__ Tm,
    const float* __restrict__ qn, const float* __restrict__ tn,
    const int* __restrict__ labels, unsigned* __restrict__ cand, int dp)
{
  __shared__ float qs[KC][68];
  __shared__ float ts[KC][148];
  __shared__ float d2s[32][65];
  __shared__ unsigned heapk[QT*KNN];
  __shared__ int labs[TT];
  int tid = threadIdx.x;
  int qbase = blockIdx.x*QT;
  int chunk = blockIdx.y;
  int n0c = chunk*CHUNK;
  int n1c = n0c+CHUNK; if (n1c > NT) n1c = NT;
  int kchunks = dp >> 5;
  for (int i=tid;i<QT*KNN;i+=256) heapk[i]=0xFFFFFFFFu;
  unsigned tau = 0xFFFFFFFFu;
  int r0 = (tid>>4)*4, c0=(tid&15)*8;
  float qnr[4];
  #pragma unroll
  for (int i=0;i<4;i++) qnr[i]=qn[qbase+r0+i];
  __syncthreads();

  for (int n0=n0c; n0<n1c; n0+=TT){
    int tl = n1c - n0; if (tl > TT) tl = TT;
    if (tid < TT){ int g=n0+tid; labs[tid] = (g<NT) ? labels[g] : 0; }
    float acc[4][8];
    #pragma unroll
    for (int i=0;i<4;i++)
      #pragma unroll
      for (int j=0;j<8;j++) acc[i][j]=0.f;

    for (int kc=0;kc<kchunks;kc++){
      { int qq0=tid>>3, k4=(tid&7)*4;
        #pragma unroll
        for (int i=0;i<2;i++){
          int qq=qq0+i*32;
          float4 v = *(const float4*)&Qm[(size_t)(qbase+qq)*dp + kc*KC + k4];
          qs[k4+0][qq]=v.x; qs[k4+1][qq]=v.y; qs[k4+2][qq]=v.z; qs[k4+3][qq]=v.w;
        }
      }
      { int tt0=tid>>3, k4=(tid&7)*4;
        #pragma unroll
        for (int i=0;i<4;i++){
          int ttI=tt0+i*32, g=n0+ttI;
          float4 v = make_float4(0.f,0.f,0.f,0.f);
          if (g < NT) v = *(const float4*)&Tm[(size_t)g*dp + kc*KC + k4];
          int o=swz(ttI);
          ts[k4+0][o]=v.x; ts[k4+1][o]=v.y; ts[k4+2][o]=v.z; ts[k4+3][o]=v.w;
        }
      }
      __syncthreads();
      #pragma unroll 8
      for (int k=0;k<KC;k++){
        float4 a  = *(const float4*)&qs[k][r0];
        float4 b0 = *(const float4*)&ts[k][swz(c0)];
        float4 b1 = *(const float4*)&ts[k][swz(c0+4)];
        float av[4]={a.x,a.y,a.z,a.w};
        float bv[8]={b0.x,b0.y,b0.z,b0.w,b1.x,b1.y,b1.z,b1.w};
        #pragma unroll
        for (int i=0;i<4;i++)
          #pragma unroll
          for (int j=0;j<8;j++) acc[i][j] += av[i]*bv[j];
      }
      __syncthreads();
    }
    // selection: quarters of 32 t-rows through d2s
    for (int quart=0; quart<4; quart++){
      int hb = quart*32;
      if ((c0>>5) == quart){
        #pragma unroll
        for (int j=0;j<8;j++){
          int g = n0+c0+j;
          float tnv = (g<NT) ? tn[g] : 0.f;
          #pragma unroll
          for (int i=0;i<4;i++){
            float d2 = qnr[i] - 2.f*acc[i][j] + tnv;
            d2 = fmaxf(d2, 0.f);
            d2s[c0-hb+j][r0+i] = d2;
          }
        }
      }
      __syncthreads();
      int tmax = tl - hb; if (tmax > 32) tmax = 32;
      if (tid < QT && tmax > 0){
        unsigned* h = &heapk[tid*KNN];
        for (int t=0;t<tmax;t++){
          float v = d2s[t][tid];
          unsigned key = (__float_as_uint(v)&0xFFFFFFF8u) | (unsigned)labs[hb+t];
          if (key < tau){
            int i=0;
            while (true){
              int l=2*i+1; if (l>=KNN) break;
              int rr=l+1;
              int m=(rr<KNN && h[rr]>h[l]) ? rr : l;
              if (h[m]>key){ h[i]=h[m]; i=m; } else break;
            }
            h[i]=key;
            tau=h[0];
          }
        }
      }
      __syncthreads();
    }
  }
  for (int i=tid;i<QT*KNN;i+=256){
    int q=i/KNN, s=i-q*KNN;
    cand[(size_t)(qbase+q)*(NCHUNK*KNN) + chunk*KNN + s] = heapk[q*KNN+s];
  }
}

// ---------------- merge per-chunk top-75 -> global top-75 -> class sums -------
__global__ __launch_bounds__(256) void merge_k(const unsigned* __restrict__ cand,
                                               float* __restrict__ tot, int first){
  __shared__ unsigned keys[NCHUNK*KNN];
  __shared__ float lsum[NL];
  __shared__ unsigned long long red[4];
  __shared__ float wsh;
  int tid=threadIdx.x, q=blockIdx.x;
  for (int i=tid;i<NCHUNK*KNN;i+=256) keys[i]=cand[(size_t)q*(NCHUNK*KNN)+i];
  if (tid<NL) lsum[tid]=0.f;
  __syncthreads();
  float wsum=0.f;
  for (int it=0; it<KNN; it++){
    unsigned bv=0xFFFFFFFFu, bi=0;
    for (int i=tid;i<NCHUNK*KNN;i+=256){
      unsigned v=keys[i];
      if (v<bv){bv=v;bi=(unsigned)i;}
    }
    unsigned long long p=((unsigned long long)bv<<32)|bi;
    #pragma unroll
    for (int off=32;off>0;off>>=1){
      unsigned long long o=__shfl_down(p,off,64);
      if (o<p) p=o;
    }
    if ((tid&63)==0) red[tid>>6]=p;
    __syncthreads();
    if (tid==0){
      p=red[0];
      if (red[1]<p)p=red[1];
      if (red[2]<p)p=red[2];
      if (red[3]<p)p=red[3];
      unsigned v=(unsigned)(p>>32);
      unsigned i=(unsigned)(p&0xFFFFFFFFu);
      keys[i]=0xFFFFFFFFu;
      if (v<0x7F800000u){
        float d2=__uint_as_float(v&0xFFFFFFF8u);
        if (d2>0.f){
          float w=1.f/sqrtf(d2);
          wsum+=w;
          lsum[v&7u]+=w;
        }
      }
    }
    __syncthreads();
  }
  if (tid==0) wsh=wsum;
  __syncthreads();
  if (tid<NL){
    float contrib=wsh-lsum[tid];
    size_t o=(size_t)q*NL+tid;
    tot[o]= first ? contrib : tot[o]+contrib;
  }
}

// ---------------- empirical p-values ------------------------------------------
__global__ void pvalue_k(const float* __restrict__ tot, const float* __restrict__ cali,
                         float* __restrict__ out){
  __shared__ float t8[NL];
  __shared__ int part[4][NL];
  int tid=threadIdx.x, q=blockIdx.x;
  if (tid<NL) t8[tid]=tot[(size_t)q*NL+tid];
  __syncthreads();
  float th[NL];
  #pragma unroll
  for (int c=0;c<NL;c++) th[c]=t8[c];
  int cnt[NL];
  #pragma unroll
  for (int c=0;c<NL;c++) cnt[c]=0;
  for (int i=tid;i<NCALI;i+=256){
    float v=cali[i];
    #pragma unroll
    for (int c=0;c<NL;c++) cnt[c] += (v>=th[c]) ? 1 : 0;
  }
  #pragma unroll
  for (int c=0;c<NL;c++){
    #pragma unroll
    for (int off=32;off>0;off>>=1) cnt[c]+=__shfl_down(cnt[c],off,64);
  }
  if ((tid&63)==0){
    #pragma unroll
    for (int c=0;c<NL;c++) part[tid>>6][c]=cnt[c];
  }
  __syncthreads();
  if (tid<NL){
    int s=part[0][tid]+part[1][tid]+part[2][tid]+part[3][tid];
    out[(size_t)q*NL+tid] = (float)s / 10000.f;
  }
}

extern "C" void kernel_launch(void* const* d_in, const int* in_sizes, int n_in,
                              void* d_out, int out_size, void* d_ws, size_t ws_size,
                              hipStream_t stream) {
  const float* x   = (const float*)d_in[0];
  const float* txr = (const float*)d_in[1];
  const int*   lbl = (const int*)  d_in[2];
  const float* cal = (const float*)d_in[3];
  const float* W1  = (const float*)d_in[4];
  const float* b1  = (const float*)d_in[5];
  const float* W2  = (const float*)d_in[6];
  const float* b2  = (const float*)d_in[7];
  const float* W3  = (const float*)d_in[8];
  const float* b3  = (const float*)d_in[9];
  const float* W4  = (const float*)d_in[10];
  const float* b4  = (const float*)d_in[11];
  float* out = (float*)d_out;
  float* ws  = (float*)d_ws;

  size_t off=0;
  float* xq0=ws+off; off+=(size_t)NB*96;
  float* xq1=ws+off; off+=(size_t)NB*128;
  float* xq2=ws+off; off+=(size_t)NB*128;
  float* xq3=ws+off; off+=(size_t)NB*128;
  float* xq4=ws+off; off+=(size_t)NB*32;
  float* tb0=ws+off; off+=(size_t)NT*96;
  float* tb1=ws+off; off+=(size_t)NT*128;
  float* tb2=ws+off; off+=(size_t)NT*128;
  float* tb3=ws+off; off+=(size_t)NT*128;
  float* tb4=ws+off; off+=(size_t)NT*32;
  float* qn =ws+off; off+=(size_t)5*NB;
  float* tnb=ws+off; off+=(size_t)5*NT;
  float* tot=ws+off; off+=(size_t)NB*NL;
  unsigned* cand=(unsigned*)(ws+off);

  // feature pads
  pad_copy_k<<<(NB*96+255)/256,256,0,stream>>>(x,   xq0, NB, 83, 96);
  pad_copy_k<<<(NT*96+255)/256,256,0,stream>>>(txr, tb0, NT, 83, 96);
  // MLP layers (queries + train bank)
  mlp_gemm_k<<<(NB+127)/128,256,0,stream>>>(xq0,96,3,W1,83,b1,xq1,NB);
  mlp_gemm_k<<<(NT+127)/128,256,0,stream>>>(tb0,96,3,W1,83,b1,tb1,NT);
  mlp_gemm_k<<<(NB+127)/128,256,0,stream>>>(xq1,128,4,W2,128,b2,xq2,NB);
  mlp_gemm_k<<<(NT+127)/128,256,0,stream>>>(tb1,128,4,W2,128,b2,tb2,NT);
  mlp_gemm_k<<<(NB+127)/128,256,0,stream>>>(xq2,128,4,W3,128,b3,xq3,NB);
  mlp_gemm_k<<<(NT+127)/128,256,0,stream>>>(tb2,128,4,W3,128,b3,tb3,NT);
  mlp8_k<<<(NB+31)/32,256,0,stream>>>(xq3,W4,b4,xq4,NB);
  mlp8_k<<<(NT+31)/32,256,0,stream>>>(tb3,W4,b4,tb4,NT);
  softmax_k<<<(NB+255)/256,256,0,stream>>>(xq4,NB);
  softmax_k<<<(NT+255)/256,256,0,stream>>>(tb4,NT);
  // row norms (after softmax!)
  rownorm_k<<<(NB+3)/4,256,0,stream>>>(xq0,qn+0*NB,NB,96);
  rownorm_k<<<(NB+3)/4,256,0,stream>>>(xq1,qn+1*NB,NB,128);
  rownorm_k<<<(NB+3)/4,256,0,stream>>>(xq2,qn+2*NB,NB,128);
  rownorm_k<<<(NB+3)/4,256,0,stream>>>(xq3,qn+3*NB,NB,128);
  rownorm_k<<<(NB+3)/4,256,0,stream>>>(xq4,qn+4*NB,NB,32);
  rownorm_k<<<(NT+3)/4,256,0,stream>>>(tb0,tnb+(size_t)0*NT,NT,96);
  rownorm_k<<<(NT+3)/4,256,0,stream>>>(tb1,tnb+(size_t)1*NT,NT,128);
  rownorm_k<<<(NT+3)/4,256,0,stream>>>(tb2,tnb+(size_t)2*NT,NT,128);
  rownorm_k<<<(NT+3)/4,256,0,stream>>>(tb3,tnb+(size_t)3*NT,NT,128);
  rownorm_k<<<(NT+3)/4,256,0,stream>>>(tb4,tnb+(size_t)4*NT,NT,32);
  // per-layer kNN + merge
  const float* Qs[5]={xq0,xq1,xq2,xq3,xq4};
  const float* Ts[5]={tb0,tb1,tb2,tb3,tb4};
  int dps[5]={96,128,128,128,32};
  for (int l=0;l<5;l++){
    dist_topk_k<<<dim3(NB/QT, NCHUNK),256,0,stream>>>(
        Qs[l],Ts[l],qn+(size_t)l*NB,tnb+(size_t)l*NT,lbl,cand,dps[l]);
    merge_k<<<NB,256,0,stream>>>(cand,tot,l==0 ? 1 : 0);
  }
  // p-values
  pvalue_k<<<NB,256,0,stream>>>(tot,cal,out);
}

// Round 2
// 4258.453 us; speedup vs baseline: 1.9921x; 1.9921x over previous
//
#include <hip/hip_runtime.h>
#include <math.h>

#define KNN 75
#define NL 8
#define NB 1024
#define NT 50000
#define NCALI 10000
#define QG 256        // queries per group (bounds key-buffer to 51.2MB)
#define NGROUP 4
#define KC 32
#define QT 64
#define TT 128
#define CAP 6144      // LDS candidate buffer for select

__device__ __forceinline__ int swz(int c){ return c + ((c>>5)<<2); }

// ---------------- pad copy (zero-fill pad cols every call: ws is poisoned) ----
__global__ void pad_copy_k(const float* __restrict__ in, float* __restrict__ out,
                           int M, int Din, int Dout){
  int idx = blockIdx.x*256 + threadIdx.x;
  if (idx >= M*Dout) return;
  int r = idx / Dout, c = idx - r*Dout;
  out[idx] = (c < Din) ? in[r*Din + c] : 0.f;
}

// ---------------- MLP GEMM: Out[M][128] = relu(A[M][lda] @ W[kreal][128] + b) --
__global__ __launch_bounds__(256) void mlp_gemm_k(
    const float* __restrict__ A, int lda, int kchunks,
    const float* __restrict__ W, int kreal,
    const float* __restrict__ bias,
    float* __restrict__ Out, int M)
{
  __shared__ float As[KC][132];
  __shared__ float Bs[KC][148];
  int tid = threadIdx.x;
  int r0 = (tid>>4)*8, c0 = (tid&15)*8;
  int rowBase = blockIdx.x*128;
  float acc[8][8];
  #pragma unroll
  for (int i=0;i<8;i++)
    #pragma unroll
    for (int j=0;j<8;j++) acc[i][j]=0.f;

  for (int kc=0;kc<kchunks;kc++){
    { int rr = tid>>3, k4=(tid&7)*4;
      #pragma unroll
      for (int i=0;i<4;i++){
        int row = rr + i*32, gr = rowBase + row;
        float4 v = make_float4(0.f,0.f,0.f,0.f);
        if (gr < M) v = *(const float4*)&A[(size_t)gr*lda + kc*KC + k4];
        As[k4+0][row]=v.x; As[k4+1][row]=v.y; As[k4+2][row]=v.z; As[k4+3][row]=v.w;
      }
    }
    { int kk=tid>>5, c4=(tid&31)*4;
      #pragma unroll
      for (int i=0;i<4;i++){
        int k = kk + i*8, gk = kc*KC + k;
        float4 v = make_float4(0.f,0.f,0.f,0.f);
        if (gk < kreal) v = *(const float4*)&W[(size_t)gk*128 + c4];
        *(float4*)&Bs[k][swz(c4)] = v;
      }
    }
    __syncthreads();
    #pragma unroll 4
    for (int k=0;k<KC;k++){
      float4 a0 = *(const float4*)&As[k][r0];
      float4 a1 = *(const float4*)&As[k][r0+4];
      float4 b0 = *(const float4*)&Bs[k][swz(c0)];
      float4 b1 = *(const float4*)&Bs[k][swz(c0+4)];
      float av[8] = {a0.x,a0.y,a0.z,a0.w,a1.x,a1.y,a1.z,a1.w};
      float bv[8] = {b0.x,b0.y,b0.z,b0.w,b1.x,b1.y,b1.z,b1.w};
      #pragma unroll
      for (int i=0;i<8;i++)
        #pragma unroll
        for (int j=0;j<8;j++) acc[i][j] += av[i]*bv[j];
    }
    __syncthreads();
  }
  float bb[8];
  #pragma unroll
  for (int j=0;j<8;j++) bb[j]=bias[c0+j];
  #pragma unroll
  for (int i=0;i<8;i++){
    int gr = rowBase + r0 + i;
    if (gr < M){
      float o[8];
      #pragma unroll
      for (int j=0;j<8;j++){ float v=acc[i][j]+bb[j]; o[j]=v>0.f?v:0.f; }
      *(float4*)&Out[(size_t)gr*128 + c0]   = make_float4(o[0],o[1],o[2],o[3]);
      *(float4*)&Out[(size_t)gr*128 + c0+4] = make_float4(o[4],o[5],o[6],o[7]);
    }
  }
}

// ---------------- last layer: logits[M][8] into stride-32 rows ----------------
__global__ void mlp8_k(const float* __restrict__ A, const float* __restrict__ W4,
                       const float* __restrict__ b4, float* __restrict__ Out, int M){
  __shared__ float Ws[128*8];
  int tid = threadIdx.x;
  for (int i=tid;i<1024;i+=256) Ws[i]=W4[i];
  __syncthreads();
  int r = blockIdx.x*32 + (tid>>3), c = tid&7;
  if (r >= M) return;
  const float* a = &A[(size_t)r*128];
  float acc = b4[c];
  #pragma unroll 16
  for (int k=0;k<128;k++) acc += a[k]*Ws[k*8+c];
  Out[(size_t)r*32 + c] = acc;
}

// ---------------- softmax over 8 logits, zero cols 8..31 ----------------------
__global__ void softmax_k(float* __restrict__ X, int M){
  int r = blockIdx.x*256 + threadIdx.x;
  if (r >= M) return;
  float* p = &X[(size_t)r*32];
  float v[8], m=-1e30f;
  #pragma unroll
  for (int j=0;j<8;j++){ v[j]=p[j]; m = v[j]>m ? v[j] : m; }
  float s=0.f;
  #pragma unroll
  for (int j=0;j<8;j++){ v[j]=__expf(v[j]-m); s+=v[j]; }
  float inv=1.f/s;
  #pragma unroll
  for (int j=0;j<8;j++) p[j]=v[j]*inv;
  #pragma unroll
  for (int j=8;j<32;j++) p[j]=0.f;
}

// ---------------- row squared-norms (one wave per row) ------------------------
__global__ void rownorm_k(const float* __restrict__ X, float* __restrict__ out,
                          int M, int dp){
  int w = threadIdx.x>>6, lane = threadIdx.x&63;
  int row = blockIdx.x*4 + w;
  if (row >= M) return;
  float s=0.f;
  for (int c=lane;c<dp;c+=64){ float v=X[(size_t)row*dp+c]; s+=v*v; }
  #pragma unroll
  for (int off=32;off>0;off>>=1) s += __shfl_down(s, off, 64);
  if (lane==0) out[row]=s;
}

// ---------------- distance GEMM -> packed keys to global ----------------------
// grid (QG/QT, ceil(NT/TT)); key = (d2bits & ~7) | label
__global__ __launch_bounds__(256) void dist_key_k(
    const float* __restrict__ Qm, const float* __restrict__ Tm,
    const float* __restrict__ qn, const float* __restrict__ tn,
    const int* __restrict__ labels, unsigned* __restrict__ keys, int dp)
{
  __shared__ float qs[KC][68];
  __shared__ float ts[KC][148];
  int tid = threadIdx.x;
  int qbase = blockIdx.x*QT;
  int n0 = blockIdx.y*TT;
  int kchunks = dp >> 5;
  int r0 = (tid>>4)*4, c0=(tid&15)*8;
  float acc[4][8];
  #pragma unroll
  for (int i=0;i<4;i++)
    #pragma unroll
    for (int j=0;j<8;j++) acc[i][j]=0.f;

  for (int kc=0;kc<kchunks;kc++){
    { int qq0=tid>>3, k4=(tid&7)*4;
      #pragma unroll
      for (int i=0;i<2;i++){
        int qq=qq0+i*32;
        float4 v = *(const float4*)&Qm[(size_t)(qbase+qq)*dp + kc*KC + k4];
        qs[k4+0][qq]=v.x; qs[k4+1][qq]=v.y; qs[k4+2][qq]=v.z; qs[k4+3][qq]=v.w;
      }
    }
    { int tt0=tid>>3, k4=(tid&7)*4;
      #pragma unroll
      for (int i=0;i<4;i++){
        int ttI=tt0+i*32, g=n0+ttI;
        float4 v = make_float4(0.f,0.f,0.f,0.f);
        if (g < NT) v = *(const float4*)&Tm[(size_t)g*dp + kc*KC + k4];
        int o=swz(ttI);
        ts[k4+0][o]=v.x; ts[k4+1][o]=v.y; ts[k4+2][o]=v.z; ts[k4+3][o]=v.w;
      }
    }
    __syncthreads();
    #pragma unroll 8
    for (int k=0;k<KC;k++){
      float4 a  = *(const float4*)&qs[k][r0];
      float4 b0 = *(const float4*)&ts[k][swz(c0)];
      float4 b1 = *(const float4*)&ts[k][swz(c0+4)];
      float av[4]={a.x,a.y,a.z,a.w};
      float bv[8]={b0.x,b0.y,b0.z,b0.w,b1.x,b1.y,b1.z,b1.w};
      #pragma unroll
      for (int i=0;i<4;i++)
        #pragma unroll
        for (int j=0;j<8;j++) acc[i][j] += av[i]*bv[j];
    }
    __syncthreads();
  }
  // epilogue: NT tiles give tl=128 or 80, both multiples of 8 -> whole 8-col
  // segments are valid-or-skipped, uint4 stores stay aligned.
  int tl = NT - n0; if (tl > TT) tl = TT;
  if (c0 < tl){
    float qnr[4];
    #pragma unroll
    for (int i=0;i<4;i++) qnr[i]=qn[qbase+r0+i];
    float tnv[8]; unsigned labv[8];
    #pragma unroll
    for (int j=0;j<8;j++){ int g=n0+c0+j; tnv[j]=tn[g]; labv[j]=(unsigned)labels[g]; }
    #pragma unroll
    for (int i=0;i<4;i++){
      unsigned kk[8];
      #pragma unroll
      for (int j=0;j<8;j++){
        float d2 = fmaxf(qnr[i] - 2.f*acc[i][j] + tnv[j], 0.f);
        kk[j] = (__float_as_uint(d2)&0xFFFFFFF8u) | labv[j];
      }
      unsigned* dst = &keys[(size_t)(qbase+r0+i)*NT + n0+c0];
      *(uint4*)dst     = make_uint4(kk[0],kk[1],kk[2],kk[3]);
      *(uint4*)(dst+4) = make_uint4(kk[4],kk[5],kk[6],kk[7]);
    }
  }
}

// ---------------- scan helper: find bin containing rank Krem ------------------
__device__ __forceinline__ void find_bin(int* hist, int* part, int nb, int Krem,
                                         int tid, int* s_B, int* s_lob){
  int ch = nb>>8;
  int s=0;
  for (int b=tid*ch;b<tid*ch+ch;b++) s+=hist[b];
  part[tid]=s;
  __syncthreads();
  if (tid==0){
    int cum=0, B=nb-1, lob=0;
    for (int t=0;t<256;t++){
      if (cum+part[t] >= Krem){
        lob=cum;
        for (int b=t*ch;b<t*ch+ch;b++){
          if (lob+hist[b]>=Krem){ B=b; break; }
          lob+=hist[b];
        }
        break;
      }
      cum+=part[t];
    }
    *s_B=B; *s_lob=lob;
  }
  __syncthreads();
}

// ---------------- exact top-75 radix select + class-sum accumulation ----------
// one block per query. keys[blockIdx.x][0..NT)
__global__ __launch_bounds__(256) void select_k(
    const unsigned* __restrict__ keys, float* __restrict__ tot, int q0, int first)
{
  __shared__ int hist[2048];
  __shared__ int part[256];
  __shared__ unsigned buf[CAP];
  __shared__ unsigned lowbuf[96];
  __shared__ int s_B, s_lob, s_cnt, s_low;
  __shared__ float s_w[9];   // [0..7]=per-label w-sum, [8]=total w-sum
  int tid=threadIdx.x;
  const unsigned* kq = keys + (size_t)blockIdx.x*NT;

#define CONTRIB(kk) do{ float d2_=__uint_as_float((kk)&0xFFFFFFF8u); \
    if (d2_>0.f){ float w_=1.0f/sqrtf(d2_); \
      atomicAdd(&s_w[8],w_); atomicAdd(&s_w[(kk)&7u],w_); } }while(0)

  int Krem = KNN;
  unsigned prefix; int shift; int c;
  // ---- round 1: bits[31:21] (top bit of key is 0: d2>=0) ----
  for (int i=tid;i<2048;i+=256) hist[i]=0;
  __syncthreads();
  { unsigned prev=0xFFFFFFFFu; int run=0;
    for (int i=tid;i<NT;i+=256){
      unsigned b=kq[i]>>21;
      if (b==prev) run++;
      else { if(run) atomicAdd(&hist[prev],run); prev=b; run=1; }
    }
    if (run) atomicAdd(&hist[prev],run);
  }
  __syncthreads();
  find_bin(hist,part,2048,Krem,tid,&s_B,&s_lob);
  c = hist[s_B]; Krem -= s_lob; prefix=(unsigned)s_B; shift=21;
  // ---- round 2 (global) only if bin too fat ----
  if (c > CAP){
    __syncthreads();
    for (int i=tid;i<2048;i+=256) hist[i]=0;
    __syncthreads();
    unsigned prev=0xFFFFFFFFu; int run=0;
    for (int i=tid;i<NT;i+=256){
      unsigned k=kq[i];
      if ((k>>21)==prefix){
        unsigned b=(k>>10)&0x7FFu;
        if (b==prev) run++;
        else { if(run) atomicAdd(&hist[prev],run); prev=b; run=1; }
      }
    }
    if (run) atomicAdd(&hist[prev],run);
    __syncthreads();
    find_bin(hist,part,2048,Krem,tid,&s_B,&s_lob);
    c = hist[s_B]; Krem -= s_lob; prefix=(prefix<<11)|(unsigned)s_B; shift=10;
  }
  // ---- round 3 (global) only if still too fat ----
  if (c > CAP){
    __syncthreads();
    for (int i=tid;i<1024;i+=256) hist[i]=0;
    __syncthreads();
    unsigned prev=0xFFFFFFFFu; int run=0;
    for (int i=tid;i<NT;i+=256){
      unsigned k=kq[i];
      if ((k>>10)==prefix){
        unsigned b=k&0x3FFu;
        if (b==prev) run++;
        else { if(run) atomicAdd(&hist[prev],run); prev=b; run=1; }
      }
    }
    if (run) atomicAdd(&hist[prev],run);
    __syncthreads();
    find_bin(hist,part,1024,Krem,tid,&s_B,&s_lob);
    c = hist[s_B]; Krem -= s_lob; prefix=(prefix<<10)|(unsigned)s_B; shift=0;
  }

  unsigned T;
  if (tid==0){ for (int j=0;j<9;j++) s_w[j]=0.f; s_cnt=0; s_low=0; }
  __syncthreads();

  if (c <= CAP){
    // collect: keys strictly below prefix-range (rank < 75 -> <=74 of them)
    // and keys inside the bin
    for (int i=tid;i<NT;i+=256){
      unsigned k=kq[i]; unsigned p=k>>shift;
      if (p==prefix){ int j=atomicAdd(&s_cnt,1); if (j<CAP) buf[j]=k; }
      else if (p<prefix){ int j=atomicAdd(&s_low,1); if (j<96) lowbuf[j]=k; }
    }
    __syncthreads();
    // pin remaining bits entirely in LDS
    int sh=shift;
    while (sh>0){
      int nsh=(sh==21)?10:0;
      int nb=1<<(sh-nsh);
      __syncthreads();
      for (int i=tid;i<nb;i+=256) hist[i]=0;
      __syncthreads();
      int cc=s_cnt;
      for (int i=tid;i<cc;i+=256) atomicAdd(&hist[(buf[i]>>nsh)&(unsigned)(nb-1)],1);
      __syncthreads();
      find_bin(hist,part,nb,Krem,tid,&s_B,&s_lob);
      Krem -= s_lob; prefix=(prefix<<(sh-nsh))|(unsigned)s_B; sh=nsh;
    }
    T = prefix;
    __syncthreads();
    int lowc=s_low, cc=s_cnt;
    for (int i=tid;i<lowc;i+=256){ unsigned k=lowbuf[i]; CONTRIB(k); }
    for (int i=tid;i<cc;i+=256){ unsigned k=buf[i]; if (k<T) CONTRIB(k); }
  } else {
    // shift==0, T fully pinned but bin has mass duplicates: direct pass
    T = prefix;
    for (int i=tid;i<NT;i+=256){ unsigned k=kq[i]; if (k<T) CONTRIB(k); }
  }
  __syncthreads();
  if (tid==0){
    // take the remaining Krem neighbors from the keys equal to T:
    // identical truncated d2 AND identical label -> identical contribution,
    // so any tie-break matches the reference sums exactly.
    float d2=__uint_as_float(T&0xFFFFFFF8u);
    float w=(d2>0.f)?(1.0f/sqrtf(d2)):0.f;
    s_w[8] += (float)Krem*w;
    s_w[T&7u] += (float)Krem*w;
  }
  __syncthreads();
  if (tid<8){
    float contrib = s_w[8]-s_w[tid];
    size_t o=(size_t)(q0+blockIdx.x)*NL+tid;
    tot[o] = first ? contrib : tot[o]+contrib;
  }
#undef CONTRIB
}

// ---------------- empirical p-values ------------------------------------------
__global__ void pvalue_k(const float* __restrict__ tot, const float* __restrict__ cali,
                         float* __restrict__ out){
  __shared__ float t8[NL];
  __shared__ int part[4][NL];
  int tid=threadIdx.x, q=blockIdx.x;
  if (tid<NL) t8[tid]=tot[(size_t)q*NL+tid];
  __syncthreads();
  float th[NL];
  #pragma unroll
  for (int c=0;c<NL;c++) th[c]=t8[c];
  int cnt[NL];
  #pragma unroll
  for (int c=0;c<NL;c++) cnt[c]=0;
  for (int i=tid;i<NCALI;i+=256){
    float v=cali[i];
    #pragma unroll
    for (int c=0;c<NL;c++) cnt[c] += (v>=th[c]) ? 1 : 0;
  }
  #pragma unroll
  for (int c=0;c<NL;c++){
    #pragma unroll
    for (int off=32;off>0;off>>=1) cnt[c]+=__shfl_down(cnt[c],off,64);
  }
  if ((tid&63)==0){
    #pragma unroll
    for (int c=0;c<NL;c++) part[tid>>6][c]=cnt[c];
  }
  __syncthreads();
  if (tid<NL){
    int s=part[0][tid]+part[1][tid]+part[2][tid]+part[3][tid];
    out[(size_t)q*NL+tid] = (float)s / 10000.f;
  }
}

extern "C" void kernel_launch(void* const* d_in, const int* in_sizes, int n_in,
                              void* d_out, int out_size, void* d_ws, size_t ws_size,
                              hipStream_t stream) {
  const float* x   = (const float*)d_in[0];
  const float* txr = (const float*)d_in[1];
  const int*   lbl = (const int*)  d_in[2];
  const float* cal = (const float*)d_in[3];
  const float* W1  = (const float*)d_in[4];
  const float* b1  = (const float*)d_in[5];
  const float* W2  = (const float*)d_in[6];
  const float* b2  = (const float*)d_in[7];
  const float* W3  = (const float*)d_in[8];
  const float* b3  = (const float*)d_in[9];
  const float* W4  = (const float*)d_in[10];
  const float* b4  = (const float*)d_in[11];
  float* out = (float*)d_out;
  float* ws  = (float*)d_ws;

  size_t off=0;
  float* xq0=ws+off; off+=(size_t)NB*128;
  float* xq1=ws+off; off+=(size_t)NB*128;
  float* xq2=ws+off; off+=(size_t)NB*128;
  float* xq3=ws+off; off+=(size_t)NB*128;
  float* xq4=ws+off; off+=(size_t)NB*32;
  float* tbA=ws+off; off+=(size_t)NT*128;
  float* tbB=ws+off; off+=(size_t)NT*128;
  float* tb4=ws+off; off+=(size_t)NT*32;
  float* qnb=ws+off; off+=(size_t)5*NB;
  float* tnb=ws+off; off+=(size_t)NT;
  float* tot=ws+off; off+=(size_t)NB*NL;
  unsigned* keys=(unsigned*)(ws+off); off+=(size_t)QG*NT;  // ~111MB total

  // query features (padded to stride 128 / 32)
  pad_copy_k<<<(NB*128+255)/256,256,0,stream>>>(x, xq0, NB, 83, 128);
  pad_copy_k<<<((size_t)NT*128+255)/256,256,0,stream>>>(txr, tbA, NT, 83, 128);
  mlp_gemm_k<<<(NB+127)/128,256,0,stream>>>(xq0,128,3,W1,83,b1,xq1,NB);
  mlp_gemm_k<<<(NB+127)/128,256,0,stream>>>(xq1,128,4,W2,128,b2,xq2,NB);
  mlp_gemm_k<<<(NB+127)/128,256,0,stream>>>(xq2,128,4,W3,128,b3,xq3,NB);
  mlp8_k<<<(NB+31)/32,256,0,stream>>>(xq3,W4,b4,xq4,NB);
  softmax_k<<<(NB+255)/256,256,0,stream>>>(xq4,NB);
  rownorm_k<<<(NB+3)/4,256,0,stream>>>(xq0,qnb+0*NB,NB,128);
  rownorm_k<<<(NB+3)/4,256,0,stream>>>(xq1,qnb+1*NB,NB,128);
  rownorm_k<<<(NB+3)/4,256,0,stream>>>(xq2,qnb+2*NB,NB,128);
  rownorm_k<<<(NB+3)/4,256,0,stream>>>(xq3,qnb+3*NB,NB,128);
  rownorm_k<<<(NB+3)/4,256,0,stream>>>(xq4,qnb+4*NB,NB,32);

  auto knn_layer = [&](const float* Qm, const float* Bank, const float* qnl,
                       int dp, int first){
    rownorm_k<<<(NT+3)/4,256,0,stream>>>(Bank,tnb,NT,dp);
    for (int g=0; g<NGROUP; g++){
      dist_key_k<<<dim3(QG/QT,(NT+TT-1)/TT),256,0,stream>>>(
          Qm+(size_t)g*QG*dp, Bank, qnl+(size_t)g*QG, tnb, lbl, keys, dp);
      select_k<<<QG,256,0,stream>>>(keys, tot, g*QG, first);
    }
  };

  // layer 0 (raw features), then rotate bank buffers A->B->A->B
  knn_layer(xq0, tbA, qnb+0*NB, 128, 1);
  mlp_gemm_k<<<(NT+127)/128,256,0,stream>>>(tbA,128,3,W1,83,b1,tbB,NT);
  knn_layer(xq1, tbB, qnb+1*NB, 128, 0);
  mlp_gemm_k<<<(NT+127)/128,256,0,stream>>>(tbB,128,4,W2,128,b2,tbA,NT);
  knn_layer(xq2, tbA, qnb+2*NB, 128, 0);
  mlp_gemm_k<<<(NT+127)/128,256,0,stream>>>(tbA,128,4,W3,128,b3,tbB,NT);
  knn_layer(xq3, tbB, qnb+3*NB, 128, 0);
  mlp8_k<<<(NT+31)/32,256,0,stream>>>(tbB,W4,b4,tb4,NT);
  softmax_k<<<(NT+255)/256,256,0,stream>>>(tb4,NT);
  knn_layer(xq4, tb4, qnb+4*NB, 32, 0);

  pvalue_k<<<NB,256,0,stream>>>(tot,cal,out);
}

// Round 3
// 3264.380 us; speedup vs baseline: 2.5987x; 1.3045x over previous
//
#include <hip/hip_runtime.h>
#include <math.h>

#define KNN 75
#define NL 8
#define NB 1024
#define NT 50000
#define NT4 12500     // NT/4 uint4 per key row
#define NCALI 10000
#define KC 32
#define QT 64
#define TT 128
#define CAP 6144      // candidate buffer per query
#define NSPLIT 8
#define CH4 1563      // uint4 chunks per split (8*1563 >= 12500)

__device__ __forceinline__ int swz(int c){ return c + ((c>>5)<<2); }

// ---------------- pad copy (zero-fill pad cols every call: ws is poisoned) ----
__global__ void pad_copy_k(const float* __restrict__ in, float* __restrict__ out,
                           int M, int Din, int Dout){
  int idx = blockIdx.x*256 + threadIdx.x;
  if (idx >= M*Dout) return;
  int r = idx / Dout, c = idx - r*Dout;
  out[idx] = (c < Din) ? in[r*Din + c] : 0.f;
}

__global__ void zero_k(int* __restrict__ p, int n){
  int i = blockIdx.x*1024 + threadIdx.x;
  if (i < n) p[i] = 0;
}

// ---------------- MLP GEMM: Out[M][128] = relu(A[M][lda] @ W[kreal][128] + b) --
__global__ __launch_bounds__(256) void mlp_gemm_k(
    const float* __restrict__ A, int lda, int kchunks,
    const float* __restrict__ W, int kreal,
    const float* __restrict__ bias,
    float* __restrict__ Out, int M)
{
  __shared__ float As[KC][132];
  __shared__ float Bs[KC][148];
  int tid = threadIdx.x;
  int r0 = (tid>>4)*8, c0 = (tid&15)*8;
  int rowBase = blockIdx.x*128;
  float acc[8][8];
  #pragma unroll
  for (int i=0;i<8;i++)
    #pragma unroll
    for (int j=0;j<8;j++) acc[i][j]=0.f;

  for (int kc=0;kc<kchunks;kc++){
    { int rr = tid>>3, k4=(tid&7)*4;
      #pragma unroll
      for (int i=0;i<4;i++){
        int row = rr + i*32, gr = rowBase + row;
        float4 v = make_float4(0.f,0.f,0.f,0.f);
        if (gr < M) v = *(const float4*)&A[(size_t)gr*lda + kc*KC + k4];
        As[k4+0][row]=v.x; As[k4+1][row]=v.y; As[k4+2][row]=v.z; As[k4+3][row]=v.w;
      }
    }
    { int kk=tid>>5, c4=(tid&31)*4;
      #pragma unroll
      for (int i=0;i<4;i++){
        int k = kk + i*8, gk = kc*KC + k;
        float4 v = make_float4(0.f,0.f,0.f,0.f);
        if (gk < kreal) v = *(const float4*)&W[(size_t)gk*128 + c4];
        *(float4*)&Bs[k][swz(c4)] = v;
      }
    }
    __syncthreads();
    #pragma unroll 4
    for (int k=0;k<KC;k++){
      float4 a0 = *(const float4*)&As[k][r0];
      float4 a1 = *(const float4*)&As[k][r0+4];
      float4 b0 = *(const float4*)&Bs[k][swz(c0)];
      float4 b1 = *(const float4*)&Bs[k][swz(c0+4)];
      float av[8] = {a0.x,a0.y,a0.z,a0.w,a1.x,a1.y,a1.z,a1.w};
      float bv[8] = {b0.x,b0.y,b0.z,b0.w,b1.x,b1.y,b1.z,b1.w};
      #pragma unroll
      for (int i=0;i<8;i++)
        #pragma unroll
        for (int j=0;j<8;j++) acc[i][j] += av[i]*bv[j];
    }
    __syncthreads();
  }
  float bb[8];
  #pragma unroll
  for (int j=0;j<8;j++) bb[j]=bias[c0+j];
  #pragma unroll
  for (int i=0;i<8;i++){
    int gr = rowBase + r0 + i;
    if (gr < M){
      float o[8];
      #pragma unroll
      for (int j=0;j<8;j++){ float v=acc[i][j]+bb[j]; o[j]=v>0.f?v:0.f; }
      *(float4*)&Out[(size_t)gr*128 + c0]   = make_float4(o[0],o[1],o[2],o[3]);
      *(float4*)&Out[(size_t)gr*128 + c0+4] = make_float4(o[4],o[5],o[6],o[7]);
    }
  }
}

// ---------------- last layer: logits[M][8] into stride-32 rows ----------------
__global__ void mlp8_k(const float* __restrict__ A, const float* __restrict__ W4,
                       const float* __restrict__ b4, float* __restrict__ Out, int M){
  __shared__ float Ws[128*8];
  int tid = threadIdx.x;
  for (int i=tid;i<1024;i+=256) Ws[i]=W4[i];
  __syncthreads();
  int r = blockIdx.x*32 + (tid>>3), c = tid&7;
  if (r >= M) return;
  const float* a = &A[(size_t)r*128];
  float acc = b4[c];
  #pragma unroll 16
  for (int k=0;k<128;k++) acc += a[k]*Ws[k*8+c];
  Out[(size_t)r*32 + c] = acc;
}

// ---------------- softmax over 8 logits, zero cols 8..31 ----------------------
__global__ void softmax_k(float* __restrict__ X, int M){
  int r = blockIdx.x*256 + threadIdx.x;
  if (r >= M) return;
  float* p = &X[(size_t)r*32];
  float v[8], m=-1e30f;
  #pragma unroll
  for (int j=0;j<8;j++){ v[j]=p[j]; m = v[j]>m ? v[j] : m; }
  float s=0.f;
  #pragma unroll
  for (int j=0;j<8;j++){ v[j]=__expf(v[j]-m); s+=v[j]; }
  float inv=1.f/s;
  #pragma unroll
  for (int j=0;j<8;j++) p[j]=v[j]*inv;
  #pragma unroll
  for (int j=8;j<32;j++) p[j]=0.f;
}

// ---------------- row squared-norms (one wave per row) ------------------------
__global__ void rownorm_k(const float* __restrict__ X, float* __restrict__ out,
                          int M, int dp){
  int w = threadIdx.x>>6, lane = threadIdx.x&63;
  int row = blockIdx.x*4 + w;
  if (row >= M) return;
  float s=0.f;
  for (int c=lane;c<dp;c+=64){ float v=X[(size_t)row*dp+c]; s+=v*v; }
  #pragma unroll
  for (int off=32;off>0;off>>=1) s += __shfl_down(s, off, 64);
  if (lane==0) out[row]=s;
}

// ---------------- distance GEMM -> packed keys to global ----------------------
// grid (qg/QT, ceil(NT/TT)); key = (d2bits & ~7) | label
__global__ __launch_bounds__(256) void dist_key_k(
    const float* __restrict__ Qm, const float* __restrict__ Tm,
    const float* __restrict__ qn, const float* __restrict__ tn,
    const int* __restrict__ labels, unsigned* __restrict__ keys, int dp)
{
  __shared__ float qs[KC][68];
  __shared__ float ts[KC][148];
  int tid = threadIdx.x;
  int qbase = blockIdx.x*QT;
  int n0 = blockIdx.y*TT;
  int kchunks = dp >> 5;
  int r0 = (tid>>4)*4, c0=(tid&15)*8;
  float acc[4][8];
  #pragma unroll
  for (int i=0;i<4;i++)
    #pragma unroll
    for (int j=0;j<8;j++) acc[i][j]=0.f;

  for (int kc=0;kc<kchunks;kc++){
    { int qq0=tid>>3, k4=(tid&7)*4;
      #pragma unroll
      for (int i=0;i<2;i++){
        int qq=qq0+i*32;
        float4 v = *(const float4*)&Qm[(size_t)(qbase+qq)*dp + kc*KC + k4];
        qs[k4+0][qq]=v.x; qs[k4+1][qq]=v.y; qs[k4+2][qq]=v.z; qs[k4+3][qq]=v.w;
      }
    }
    { int tt0=tid>>3, k4=(tid&7)*4;
      #pragma unroll
      for (int i=0;i<4;i++){
        int ttI=tt0+i*32, g=n0+ttI;
        float4 v = make_float4(0.f,0.f,0.f,0.f);
        if (g < NT) v = *(const float4*)&Tm[(size_t)g*dp + kc*KC + k4];
        int o=swz(ttI);
        ts[k4+0][o]=v.x; ts[k4+1][o]=v.y; ts[k4+2][o]=v.z; ts[k4+3][o]=v.w;
      }
    }
    __syncthreads();
    #pragma unroll 8
    for (int k=0;k<KC;k++){
      float4 a  = *(const float4*)&qs[k][r0];
      float4 b0 = *(const float4*)&ts[k][swz(c0)];
      float4 b1 = *(const float4*)&ts[k][swz(c0+4)];
      float av[4]={a.x,a.y,a.z,a.w};
      float bv[8]={b0.x,b0.y,b0.z,b0.w,b1.x,b1.y,b1.z,b1.w};
      #pragma unroll
      for (int i=0;i<4;i++)
        #pragma unroll
        for (int j=0;j<8;j++) acc[i][j] += av[i]*bv[j];
    }
    __syncthreads();
  }
  int tl = NT - n0; if (tl > TT) tl = TT;
  if (c0 < tl){
    float qnr[4];
    #pragma unroll
    for (int i=0;i<4;i++) qnr[i]=qn[qbase+r0+i];
    float tnv[8]; unsigned labv[8];
    #pragma unroll
    for (int j=0;j<8;j++){ int g=n0+c0+j; tnv[j]=tn[g]; labv[j]=(unsigned)labels[g]; }
    #pragma unroll
    for (int i=0;i<4;i++){
      unsigned kk[8];
      #pragma unroll
      for (int j=0;j<8;j++){
        float d2 = fmaxf(qnr[i] - 2.f*acc[i][j] + tnv[j], 0.f);
        kk[j] = (__float_as_uint(d2)&0xFFFFFFF8u) | labv[j];
      }
      unsigned* dst = &keys[(size_t)(qbase+r0+i)*NT + n0+c0];
      *(uint4*)dst     = make_uint4(kk[0],kk[1],kk[2],kk[3]);
      *(uint4*)(dst+4) = make_uint4(kk[4],kk[5],kk[6],kk[7]);
    }
  }
}

// ---------------- split-parallel coarse histogram (bits[31:21]) ---------------
// grid (NSPLIT, qg)
__global__ __launch_bounds__(256) void hist_k(const unsigned* __restrict__ keys,
                                              int* __restrict__ hist){
  __shared__ int h[2048];
  int tid=threadIdx.x, split=blockIdx.x, q=blockIdx.y;
  for (int i=tid;i<2048;i+=256) h[i]=0;
  __syncthreads();
  const uint4* row=(const uint4*)(keys+(size_t)q*NT);
  int base=split*CH4;
  int end=base+CH4; if (end>NT4) end=NT4;
  for (int i=base+tid;i<end;i+=256){
    uint4 v=row[i];
    atomicAdd(&h[v.x>>21],1);
    atomicAdd(&h[v.y>>21],1);
    atomicAdd(&h[v.z>>21],1);
    atomicAdd(&h[v.w>>21],1);
  }
  __syncthreads();
  int* gh=hist+(size_t)q*2048;
  for (int i=tid;i<2048;i+=256){ int c=h[i]; if (c) atomicAdd(&gh[i],c); }
}

// ---------------- scan helper: find bin containing rank Krem ------------------
__device__ __forceinline__ void find_bin(int* hist, int* part, int nb, int Krem,
                                         int tid, int* s_B, int* s_lob){
  int ch = nb>>8;
  int s=0;
  for (int b=tid*ch;b<tid*ch+ch;b++) s+=hist[b];
  part[tid]=s;
  __syncthreads();
  if (tid==0){
    int cum=0, B=nb-1, lob=0;
    for (int t=0;t<256;t++){
      if (cum+part[t] >= Krem){
        lob=cum;
        for (int b=t*ch;b<t*ch+ch;b++){
          if (lob+hist[b]>=Krem){ B=b; break; }
          lob+=hist[b];
        }
        break;
      }
      cum+=part[t];
    }
    *s_B=B; *s_lob=lob;
  }
  __syncthreads();
}

// ---------------- per-query plan: cutoff bin, Krem, mode ----------------------
// grid qg. plan[q] = {mode, B1, Krem(=75-lob1), c1}; also zeroes ccnt[q]
__global__ __launch_bounds__(256) void plan_k(const int* __restrict__ hist,
                                              int* __restrict__ plan,
                                              int* __restrict__ ccnt){
  __shared__ int h[2048];
  __shared__ int part[256];
  __shared__ int sB, sLob;
  int tid=threadIdx.x, q=blockIdx.x;
  const int* gh=hist+(size_t)q*2048;
  for (int i=tid;i<2048;i+=256) h[i]=gh[i];
  __syncthreads();
  find_bin(h,part,2048,KNN,tid,&sB,&sLob);
  if (tid==0){
    int c=h[sB];
    int* p=plan+q*4;
    p[0]=(sLob + c <= CAP) ? 0 : 1;
    p[1]=sB; p[2]=KNN-sLob; p[3]=c;
    ccnt[q]=0;
  }
}

// ---------------- split-parallel candidate compaction -------------------------
// grid (NSPLIT, qg). mode-0 only: gather keys < (B1+1)<<21 (count <= CAP)
__global__ __launch_bounds__(256) void collect_k(const unsigned* __restrict__ keys,
                                                 const int* __restrict__ plan,
                                                 unsigned* __restrict__ cand,
                                                 int* __restrict__ ccnt){
  int tid=threadIdx.x, split=blockIdx.x, q=blockIdx.y;
  const int* p=plan+q*4;
  if (p[0]!=0) return;
  unsigned Thi=((unsigned)p[1]+1u)<<21;
  const uint4* row=(const uint4*)(keys+(size_t)q*NT);
  unsigned* cq=cand+(size_t)q*CAP;
  int base=split*CH4;
  int end=base+CH4; if (end>NT4) end=NT4;
  for (int i=base+tid;i<end;i+=256){
    uint4 v=row[i];
    if (v.x<Thi){ int j=atomicAdd(&ccnt[q],1); cq[j]=v.x; }
    if (v.y<Thi){ int j=atomicAdd(&ccnt[q],1); cq[j]=v.y; }
    if (v.z<Thi){ int j=atomicAdd(&ccnt[q],1); cq[j]=v.z; }
    if (v.w<Thi){ int j=atomicAdd(&ccnt[q],1); cq[j]=v.w; }
  }
}

// ---------------- exact select over candidates + class sums -------------------
// grid qg, one block per query
__global__ __launch_bounds__(256) void final_k(
    const unsigned* __restrict__ keys, const unsigned* __restrict__ cand,
    const int* __restrict__ ccnt, const int* __restrict__ plan,
    float* __restrict__ tot, int q0, int first)
{
  __shared__ int hist[2048];
  __shared__ int part[256];
  __shared__ unsigned buf[CAP];
  __shared__ unsigned lowbuf[96];
  __shared__ int sB,sLob,s_cnt,s_low;
  __shared__ float s_w[9];
  int tid=threadIdx.x, q=blockIdx.x;
  const int* p=plan+q*4;
  int mode=p[0];
  if (tid==0){ for (int j=0;j<9;j++) s_w[j]=0.f; s_cnt=0; s_low=0; }
  __syncthreads();

#define CONTRIB(kk) do{ float d2_=__uint_as_float((kk)&0xFFFFFFF8u); \
    if (d2_>0.f){ float w_=1.0f/sqrtf(d2_); \
      atomicAdd(&s_w[8],w_); atomicAdd(&s_w[(kk)&7u],w_); } }while(0)

  unsigned T; int Krem;
  if (mode==0){
    int cnt=ccnt[q];
    for (int i=tid;i<cnt;i+=256) buf[i]=cand[(size_t)q*CAP+i];
    __syncthreads();
    Krem=KNN;
    // pass 0: bits[31:21]
    for (int i=tid;i<2048;i+=256) hist[i]=0;
    __syncthreads();
    for (int i=tid;i<cnt;i+=256) atomicAdd(&hist[buf[i]>>21],1);
    __syncthreads();
    find_bin(hist,part,2048,Krem,tid,&sB,&sLob);
    unsigned pre=(unsigned)sB; Krem-=sLob;
    // pass 1: bits[20:10]
    for (int i=tid;i<2048;i+=256) hist[i]=0;
    __syncthreads();
    for (int i=tid;i<cnt;i+=256){ unsigned k=buf[i]; if ((k>>21)==pre) atomicAdd(&hist[(k>>10)&0x7FFu],1); }
    __syncthreads();
    find_bin(hist,part,2048,Krem,tid,&sB,&sLob);
    pre=(pre<<11)|(unsigned)sB; Krem-=sLob;
    // pass 2: bits[9:0]
    for (int i=tid;i<1024;i+=256) hist[i]=0;
    __syncthreads();
    for (int i=tid;i<cnt;i+=256){ unsigned k=buf[i]; if ((k>>10)==pre) atomicAdd(&hist[k&0x3FFu],1); }
    __syncthreads();
    find_bin(hist,part,1024,Krem,tid,&sB,&sLob);
    T=(pre<<10)|(unsigned)sB; Krem-=sLob;
    __syncthreads();
    for (int i=tid;i<cnt;i+=256){ unsigned k=buf[i]; if (k<T) CONTRIB(k); }
  } else {
    // fallback: full-row refine (rare). Matches round-2 logic.
    const unsigned* kq = keys + (size_t)q*NT;
    Krem=p[2];
    unsigned prefix=(unsigned)p[1]; int shift=21; int c=p[3];
    if (c > CAP){
      for (int i=tid;i<2048;i+=256) hist[i]=0;
      __syncthreads();
      for (int i=tid;i<NT;i+=256){
        unsigned k=kq[i];
        if ((k>>21)==prefix) atomicAdd(&hist[(k>>10)&0x7FFu],1);
      }
      __syncthreads();
      find_bin(hist,part,2048,Krem,tid,&sB,&sLob);
      c=hist[sB]; Krem-=sLob; prefix=(prefix<<11)|(unsigned)sB; shift=10;
    }
    if (c > CAP){
      __syncthreads();
      for (int i=tid;i<1024;i+=256) hist[i]=0;
      __syncthreads();
      for (int i=tid;i<NT;i+=256){
        unsigned k=kq[i];
        if ((k>>10)==prefix) atomicAdd(&hist[k&0x3FFu],1);
      }
      __syncthreads();
      find_bin(hist,part,1024,Krem,tid,&sB,&sLob);
      c=hist[sB]; Krem-=sLob; prefix=(prefix<<10)|(unsigned)sB; shift=0;
    }
    if (c <= CAP){
      for (int i=tid;i<NT;i+=256){
        unsigned k=kq[i]; unsigned pp=k>>shift;
        if (pp==prefix){ int j=atomicAdd(&s_cnt,1); if (j<CAP) buf[j]=k; }
        else if (pp<prefix){ int j=atomicAdd(&s_low,1); if (j<96) lowbuf[j]=k; }
      }
      __syncthreads();
      int sh=shift;
      while (sh>0){
        int nsh=(sh==21)?10:0;
        int nb=1<<(sh-nsh);
        __syncthreads();
        for (int i=tid;i<nb;i+=256) hist[i]=0;
        __syncthreads();
        int cc=s_cnt;
        for (int i=tid;i<cc;i+=256) atomicAdd(&hist[(buf[i]>>nsh)&(unsigned)(nb-1)],1);
        __syncthreads();
        find_bin(hist,part,nb,Krem,tid,&sB,&sLob);
        Krem-=sLob; prefix=(prefix<<(sh-nsh))|(unsigned)sB; sh=nsh;
      }
      T=prefix;
      __syncthreads();
      int lowc=s_low, cc=s_cnt;
      for (int i=tid;i<lowc;i+=256){ unsigned k=lowbuf[i]; CONTRIB(k); }
      for (int i=tid;i<cc;i+=256){ unsigned k=buf[i]; if (k<T) CONTRIB(k); }
    } else {
      T=prefix;  // shift==0: mass duplicates
      for (int i=tid;i<NT;i+=256){ unsigned k=kq[i]; if (k<T) CONTRIB(k); }
    }
  }
  __syncthreads();
  if (tid==0){
    // remaining Krem neighbors all have key == T (same truncated d2 AND label)
    float d2=__uint_as_float(T&0xFFFFFFF8u);
    float w=(d2>0.f)?(1.0f/sqrtf(d2)):0.f;
    s_w[8] += (float)Krem*w;
    s_w[T&7u] += (float)Krem*w;
  }
  __syncthreads();
  if (tid<8){
    float contrib = s_w[8]-s_w[tid];
    size_t o=(size_t)(q0+q)*NL+tid;
    tot[o] = first ? contrib : tot[o]+contrib;
  }
#undef CONTRIB
}

// ---------------- empirical p-values ------------------------------------------
__global__ void pvalue_k(const float* __restrict__ tot, const float* __restrict__ cali,
                         float* __restrict__ out){
  __shared__ float t8[NL];
  __shared__ int part[4][NL];
  int tid=threadIdx.x, q=blockIdx.x;
  if (tid<NL) t8[tid]=tot[(size_t)q*NL+tid];
  __syncthreads();
  float th[NL];
  #pragma unroll
  for (int c=0;c<NL;c++) th[c]=t8[c];
  int cnt[NL];
  #pragma unroll
  for (int c=0;c<NL;c++) cnt[c]=0;
  for (int i=tid;i<NCALI;i+=256){
    float v=cali[i];
    #pragma unroll
    for (int c=0;c<NL;c++) cnt[c] += (v>=th[c]) ? 1 : 0;
  }
  #pragma unroll
  for (int c=0;c<NL;c++){
    #pragma unroll
    for (int off=32;off>0;off>>=1) cnt[c]+=__shfl_down(cnt[c],off,64);
  }
  if ((tid&63)==0){
    #pragma unroll
    for (int c=0;c<NL;c++) part[tid>>6][c]=cnt[c];
  }
  __syncthreads();
  if (tid<NL){
    int s=part[0][tid]+part[1][tid]+part[2][tid]+part[3][tid];
    out[(size_t)q*NL+tid] = (float)s / 10000.f;
  }
}

extern "C" void kernel_launch(void* const* d_in, const int* in_sizes, int n_in,
                              void* d_out, int out_size, void* d_ws, size_t ws_size,
                              hipStream_t stream) {
  const float* x   = (const float*)d_in[0];
  const float* txr = (const float*)d_in[1];
  const int*   lbl = (const int*)  d_in[2];
  const float* cal = (const float*)d_in[3];
  const float* W1  = (const float*)d_in[4];
  const float* b1  = (const float*)d_in[5];
  const float* W2  = (const float*)d_in[6];
  const float* b2  = (const float*)d_in[7];
  const float* W3  = (const float*)d_in[8];
  const float* b3  = (const float*)d_in[9];
  const float* W4  = (const float*)d_in[10];
  const float* b4  = (const float*)d_in[11];
  float* out = (float*)d_out;
  float* ws  = (float*)d_ws;

  // fixed float allocations
  size_t fixed_f = (size_t)NB*(96+128*3+32) + 2*(size_t)NT*128 + (size_t)NT*32
                 + 5*NB + NT + (size_t)NB*NL + 64;
  // per-query select-buffer bytes: keys + cand + hist + plan + ccnt
  size_t perq = (size_t)NT*4 + (size_t)CAP*4 + 2048*4 + 16 + 4;
  int qg = 128;
  if (fixed_f*4 + 512*perq <= ws_size) qg = 512;
  else if (fixed_f*4 + 256*perq <= ws_size) qg = 256;
  int ngroup = NB/qg;

  size_t off=0;
  float* xq0=ws+off; off+=(size_t)NB*96;
  float* xq1=ws+off; off+=(size_t)NB*128;
  float* xq2=ws+off; off+=(size_t)NB*128;
  float* xq3=ws+off; off+=(size_t)NB*128;
  float* xq4=ws+off; off+=(size_t)NB*32;
  float* tbA=ws+off; off+=(size_t)NT*128;
  float* tbB=ws+off; off+=(size_t)NT*128;
  float* tb4=ws+off; off+=(size_t)NT*32;
  float* qnb=ws+off; off+=(size_t)5*NB;
  float* tnb=ws+off; off+=(size_t)NT;
  float* tot=ws+off; off+=(size_t)NB*NL;
  off=(off+3)&~(size_t)3;
  int* hist=(int*)(ws+off);      off+=(size_t)qg*2048;
  int* plan=(int*)(ws+off);      off+=(size_t)qg*4;
  int* ccnt=(int*)(ws+off);      off+=(size_t)qg;
  off=(off+3)&~(size_t)3;
  unsigned* cand=(unsigned*)(ws+off); off+=(size_t)qg*CAP;
  unsigned* keys=(unsigned*)(ws+off); off+=(size_t)qg*NT;

  // query features; layer-0 features at stride 96 (saves 25% of layer-0 dist)
  pad_copy_k<<<(NB*96+255)/256,256,0,stream>>>(x, xq0, NB, 83, 96);
  pad_copy_k<<<((size_t)NT*96+255)/256,256,0,stream>>>(txr, tbA, NT, 83, 96);
  mlp_gemm_k<<<(NB+127)/128,256,0,stream>>>(xq0,96,3,W1,83,b1,xq1,NB);
  mlp_gemm_k<<<(NB+127)/128,256,0,stream>>>(xq1,128,4,W2,128,b2,xq2,NB);
  mlp_gemm_k<<<(NB+127)/128,256,0,stream>>>(xq2,128,4,W3,128,b3,xq3,NB);
  mlp8_k<<<(NB+31)/32,256,0,stream>>>(xq3,W4,b4,xq4,NB);
  softmax_k<<<(NB+255)/256,256,0,stream>>>(xq4,NB);
  rownorm_k<<<(NB+3)/4,256,0,stream>>>(xq0,qnb+0*NB,NB,96);
  rownorm_k<<<(NB+3)/4,256,0,stream>>>(xq1,qnb+1*NB,NB,128);
  rownorm_k<<<(NB+3)/4,256,0,stream>>>(xq2,qnb+2*NB,NB,128);
  rownorm_k<<<(NB+3)/4,256,0,stream>>>(xq3,qnb+3*NB,NB,128);
  rownorm_k<<<(NB+3)/4,256,0,stream>>>(xq4,qnb+4*NB,NB,32);

  auto knn_layer = [&](const float* Qm, const float* Bank, const float* qnl,
                       int dp, int first){
    rownorm_k<<<(NT+3)/4,256,0,stream>>>(Bank,tnb,NT,dp);
    for (int g=0; g<ngroup; g++){
      zero_k<<<(qg*2048+1023)/1024,1024,0,stream>>>(hist, qg*2048);
      dist_key_k<<<dim3(qg/QT,(NT+TT-1)/TT),256,0,stream>>>(
          Qm+(size_t)g*qg*dp, Bank, qnl+(size_t)g*qg, tnb, lbl, keys, dp);
      hist_k<<<dim3(NSPLIT,qg),256,0,stream>>>(keys, hist);
      plan_k<<<qg,256,0,stream>>>(hist, plan, ccnt);
      collect_k<<<dim3(NSPLIT,qg),256,0,stream>>>(keys, plan, cand, ccnt);
      final_k<<<qg,256,0,stream>>>(keys, cand, ccnt, plan, tot, g*qg, first);
    }
  };

  knn_layer(xq0, tbA, qnb+0*NB, 96, 1);
  mlp_gemm_k<<<(NT+127)/128,256,0,stream>>>(tbA,96,3,W1,83,b1,tbB,NT);
  knn_layer(xq1, tbB, qnb+1*NB, 128, 0);
  mlp_gemm_k<<<(NT+127)/128,256,0,stream>>>(tbB,128,4,W2,128,b2,tbA,NT);
  knn_layer(xq2, tbA, qnb+2*NB, 128, 0);
  mlp_gemm_k<<<(NT+127)/128,256,0,stream>>>(tbA,128,4,W3,128,b3,tbB,NT);
  knn_layer(xq3, tbB, qnb+3*NB, 128, 0);
  mlp8_k<<<(NT+31)/32,256,0,stream>>>(tbB,W4,b4,tb4,NT);
  softmax_k<<<(NT+255)/256,256,0,stream>>>(tb4,NT);
  knn_layer(xq4, tb4, qnb+4*NB, 32, 0);

  pvalue_k<<<NB,256,0,stream>>>(tot,cal,out);
}

// Round 4
// 2935.165 us; speedup vs baseline: 2.8902x; 1.1122x over previous
//
#include <hip/hip_runtime.h>
#include <math.h>

#define KNN 75
#define NL 8
#define NB 1024
#define NT 50000
#define NCALI 10000
#define KC 32
#define QT 64
#define TT 128
#define CAP 6144      // candidate buffer per query
#define NSUB 2048     // sampled train points for threshold
#define SSTRIDE 24
#define SOFF 11       // 11 + 24*2047 = 49139 < 50000
#define RSEL 64       // sample rank used as threshold (exp. count ~1562)

__device__ __forceinline__ int swz(int c){ return c + ((c>>5)<<2); }

// ---------------- pad copy (zero-fill pad cols every call: ws is poisoned) ----
__global__ void pad_copy_k(const float* __restrict__ in, float* __restrict__ out,
                           int M, int Din, int Dout){
  int idx = blockIdx.x*256 + threadIdx.x;
  if (idx >= M*Dout) return;
  int r = idx / Dout, c = idx - r*Dout;
  out[idx] = (c < Din) ? in[r*Din + c] : 0.f;
}

// ---------------- MLP GEMM: Out[M][128] = relu(A[M][lda] @ W[kreal][128] + b) --
__global__ __launch_bounds__(256) void mlp_gemm_k(
    const float* __restrict__ A, int lda, int kchunks,
    const float* __restrict__ W, int kreal,
    const float* __restrict__ bias,
    float* __restrict__ Out, int M)
{
  __shared__ float As[KC][132];
  __shared__ float Bs[KC][148];
  int tid = threadIdx.x;
  int r0 = (tid>>4)*8, c0 = (tid&15)*8;
  int rowBase = blockIdx.x*128;
  float acc[8][8];
  #pragma unroll
  for (int i=0;i<8;i++)
    #pragma unroll
    for (int j=0;j<8;j++) acc[i][j]=0.f;

  for (int kc=0;kc<kchunks;kc++){
    { int rr = tid>>3, k4=(tid&7)*4;
      #pragma unroll
      for (int i=0;i<4;i++){
        int row = rr + i*32, gr = rowBase + row;
        float4 v = make_float4(0.f,0.f,0.f,0.f);
        if (gr < M) v = *(const float4*)&A[(size_t)gr*lda + kc*KC + k4];
        As[k4+0][row]=v.x; As[k4+1][row]=v.y; As[k4+2][row]=v.z; As[k4+3][row]=v.w;
      }
    }
    { int kk=tid>>5, c4=(tid&31)*4;
      #pragma unroll
      for (int i=0;i<4;i++){
        int k = kk + i*8, gk = kc*KC + k;
        float4 v = make_float4(0.f,0.f,0.f,0.f);
        if (gk < kreal) v = *(const float4*)&W[(size_t)gk*128 + c4];
        *(float4*)&Bs[k][swz(c4)] = v;
      }
    }
    __syncthreads();
    #pragma unroll 4
    for (int k=0;k<KC;k++){
      float4 a0 = *(const float4*)&As[k][r0];
      float4 a1 = *(const float4*)&As[k][r0+4];
      float4 b0 = *(const float4*)&Bs[k][swz(c0)];
      float4 b1 = *(const float4*)&Bs[k][swz(c0+4)];
      float av[8] = {a0.x,a0.y,a0.z,a0.w,a1.x,a1.y,a1.z,a1.w};
      float bv[8] = {b0.x,b0.y,b0.z,b0.w,b1.x,b1.y,b1.z,b1.w};
      #pragma unroll
      for (int i=0;i<8;i++)
        #pragma unroll
        for (int j=0;j<8;j++) acc[i][j] += av[i]*bv[j];
    }
    __syncthreads();
  }
  float bb[8];
  #pragma unroll
  for (int j=0;j<8;j++) bb[j]=bias[c0+j];
  #pragma unroll
  for (int i=0;i<8;i++){
    int gr = rowBase + r0 + i;
    if (gr < M){
      float o[8];
      #pragma unroll
      for (int j=0;j<8;j++){ float v=acc[i][j]+bb[j]; o[j]=v>0.f?v:0.f; }
      *(float4*)&Out[(size_t)gr*128 + c0]   = make_float4(o[0],o[1],o[2],o[3]);
      *(float4*)&Out[(size_t)gr*128 + c0+4] = make_float4(o[4],o[5],o[6],o[7]);
    }
  }
}

// ---------------- last layer: logits[M][8] into stride-32 rows ----------------
__global__ void mlp8_k(const float* __restrict__ A, const float* __restrict__ W4,
                       const float* __restrict__ b4, float* __restrict__ Out, int M){
  __shared__ float Ws[128*8];
  int tid = threadIdx.x;
  for (int i=tid;i<1024;i+=256) Ws[i]=W4[i];
  __syncthreads();
  int r = blockIdx.x*32 + (tid>>3), c = tid&7;
  if (r >= M) return;
  const float* a = &A[(size_t)r*128];
  float acc = b4[c];
  #pragma unroll 16
  for (int k=0;k<128;k++) acc += a[k]*Ws[k*8+c];
  Out[(size_t)r*32 + c] = acc;
}

// ---------------- softmax over 8 logits, zero cols 8..31 ----------------------
__global__ void softmax_k(float* __restrict__ X, int M){
  int r = blockIdx.x*256 + threadIdx.x;
  if (r >= M) return;
  float* p = &X[(size_t)r*32];
  float v[8], m=-1e30f;
  #pragma unroll
  for (int j=0;j<8;j++){ v[j]=p[j]; m = v[j]>m ? v[j] : m; }
  float s=0.f;
  #pragma unroll
  for (int j=0;j<8;j++){ v[j]=__expf(v[j]-m); s+=v[j]; }
  float inv=1.f/s;
  #pragma unroll
  for (int j=0;j<8;j++) p[j]=v[j]*inv;
  #pragma unroll
  for (int j=8;j<32;j++) p[j]=0.f;
}

// ---------------- row squared-norms (one wave per row) ------------------------
__global__ void rownorm_k(const float* __restrict__ X, float* __restrict__ out,
                          int M, int dp){
  int w = threadIdx.x>>6, lane = threadIdx.x&63;
  int row = blockIdx.x*4 + w;
  if (row >= M) return;
  float s=0.f;
  for (int c=lane;c<dp;c+=64){ float v=X[(size_t)row*dp+c]; s+=v*v; }
  #pragma unroll
  for (int off=32;off>0;off>>=1) s += __shfl_down(s, off, 64);
  if (lane==0) out[row]=s;
}

// ---------------- gather sampled subset bank + its norms ----------------------
__global__ void sub_gather_k(const float* __restrict__ Bank, const float* __restrict__ tnb,
                             float* __restrict__ Tsub, float* __restrict__ tnsub, int dp){
  int idx = blockIdx.x*256 + threadIdx.x;
  int total = NSUB*dp;
  if (idx < total){
    int s = idx/dp, c = idx - s*dp;
    Tsub[idx] = Bank[(size_t)(s*SSTRIDE+SOFF)*dp + c];
  } else if (idx < total + NSUB){
    int s = idx - total;
    tnsub[s] = tnb[s*SSTRIDE+SOFF];
  }
}

// ---------------- subset distance GEMM -> packed keys -------------------------
// grid (NB/QT, nt/TT); key = (d2bits & ~7) | label  (labels approximate: ok,
// keys are only used to pick a threshold value)
__global__ __launch_bounds__(256) void dist_key_k(
    const float* __restrict__ Qm, const float* __restrict__ Tm,
    const float* __restrict__ qn, const float* __restrict__ tn,
    const int* __restrict__ labels, unsigned* __restrict__ keys, int dp, int nt)
{
  __shared__ float qs[KC][68];
  __shared__ float ts[KC][148];
  int tid = threadIdx.x;
  int qbase = blockIdx.x*QT;
  int n0 = blockIdx.y*TT;
  int kchunks = dp >> 5;
  int r0 = (tid>>4)*4, c0=(tid&15)*8;
  float acc[4][8];
  #pragma unroll
  for (int i=0;i<4;i++)
    #pragma unroll
    for (int j=0;j<8;j++) acc[i][j]=0.f;

  for (int kc=0;kc<kchunks;kc++){
    { int qq0=tid>>3, k4=(tid&7)*4;
      #pragma unroll
      for (int i=0;i<2;i++){
        int qq=qq0+i*32;
        float4 v = *(const float4*)&Qm[(size_t)(qbase+qq)*dp + kc*KC + k4];
        qs[k4+0][qq]=v.x; qs[k4+1][qq]=v.y; qs[k4+2][qq]=v.z; qs[k4+3][qq]=v.w;
      }
    }
    { int tt0=tid>>3, k4=(tid&7)*4;
      #pragma unroll
      for (int i=0;i<4;i++){
        int ttI=tt0+i*32, g=n0+ttI;
        float4 v = make_float4(0.f,0.f,0.f,0.f);
        if (g < nt) v = *(const float4*)&Tm[(size_t)g*dp + kc*KC + k4];
        int o=swz(ttI);
        ts[k4+0][o]=v.x; ts[k4+1][o]=v.y; ts[k4+2][o]=v.z; ts[k4+3][o]=v.w;
      }
    }
    __syncthreads();
    #pragma unroll 8
    for (int k=0;k<KC;k++){
      float4 a  = *(const float4*)&qs[k][r0];
      float4 b0 = *(const float4*)&ts[k][swz(c0)];
      float4 b1 = *(const float4*)&ts[k][swz(c0+4)];
      float av[4]={a.x,a.y,a.z,a.w};
      float bv[8]={b0.x,b0.y,b0.z,b0.w,b1.x,b1.y,b1.z,b1.w};
      #pragma unroll
      for (int i=0;i<4;i++)
        #pragma unroll
        for (int j=0;j<8;j++) acc[i][j] += av[i]*bv[j];
    }
    __syncthreads();
  }
  int tl = nt - n0; if (tl > TT) tl = TT;
  if (c0 < tl){
    float qnr[4];
    #pragma unroll
    for (int i=0;i<4;i++) qnr[i]=qn[qbase+r0+i];
    float tnv[8]; unsigned labv[8];
    #pragma unroll
    for (int j=0;j<8;j++){ int g=n0+c0+j; tnv[j]=tn[g]; labv[j]=(unsigned)labels[g]; }
    #pragma unroll
    for (int i=0;i<4;i++){
      unsigned kk[8];
      #pragma unroll
      for (int j=0;j<8;j++){
        float d2 = fmaxf(qnr[i] - 2.f*acc[i][j] + tnv[j], 0.f);
        kk[j] = (__float_as_uint(d2)&0xFFFFFFF8u) | labv[j];
      }
      unsigned* dst = &keys[(size_t)(qbase+r0+i)*nt + n0+c0];
      *(uint4*)dst     = make_uint4(kk[0],kk[1],kk[2],kk[3]);
      *(uint4*)(dst+4) = make_uint4(kk[4],kk[5],kk[6],kk[7]);
    }
  }
}

// ---------------- scan helper: find bin containing rank Krem ------------------
__device__ __forceinline__ void find_bin(int* hist, int* part, int nb, int Krem,
                                         int tid, int* s_B, int* s_lob){
  int ch = nb>>8;
  int s=0;
  for (int b=tid*ch;b<tid*ch+ch;b++) s+=hist[b];
  part[tid]=s;
  __syncthreads();
  if (tid==0){
    int cum=0, B=nb-1, lob=0;
    for (int t=0;t<256;t++){
      if (cum+part[t] >= Krem){
        lob=cum;
        for (int b=t*ch;b<t*ch+ch;b++){
          if (lob+hist[b]>=Krem){ B=b; break; }
          lob+=hist[b];
        }
        break;
      }
      cum+=part[t];
    }
    *s_B=B; *s_lob=lob;
  }
  __syncthreads();
}

// ---------------- per-query threshold: exact RSEL-th smallest sample key ------
__global__ __launch_bounds__(256) void sel64_k(const unsigned* __restrict__ skeys,
                                               unsigned* __restrict__ Tthr,
                                               int* __restrict__ ccnt){
  __shared__ unsigned buf[NSUB];
  __shared__ int hist[2048];
  __shared__ int part[256];
  __shared__ int sB, sLob;
  int tid=threadIdx.x, q=blockIdx.x;
  for (int i=tid;i<NSUB;i+=256) buf[i]=skeys[(size_t)q*NSUB+i];
  int Krem=RSEL;
  for (int i=tid;i<2048;i+=256) hist[i]=0;
  __syncthreads();
  for (int i=tid;i<NSUB;i+=256) atomicAdd(&hist[buf[i]>>21],1);
  __syncthreads();
  find_bin(hist,part,2048,Krem,tid,&sB,&sLob);
  unsigned pre=(unsigned)sB; Krem-=sLob;
  for (int i=tid;i<2048;i+=256) hist[i]=0;
  __syncthreads();
  for (int i=tid;i<NSUB;i+=256){ unsigned k=buf[i]; if ((k>>21)==pre) atomicAdd(&hist[(k>>10)&0x7FFu],1); }
  __syncthreads();
  find_bin(hist,part,2048,Krem,tid,&sB,&sLob);
  pre=(pre<<11)|(unsigned)sB; Krem-=sLob;
  for (int i=tid;i<1024;i+=256) hist[i]=0;
  __syncthreads();
  for (int i=tid;i<NSUB;i+=256){ unsigned k=buf[i]; if ((k>>10)==pre) atomicAdd(&hist[k&0x3FFu],1); }
  __syncthreads();
  find_bin(hist,part,1024,Krem,tid,&sB,&sLob);
  if (tid==0){ Tthr[q]=(pre<<10)|(unsigned)sB; ccnt[q]=0; }
}

// ---------------- fused distance GEMM + threshold compaction ------------------
// grid (NB/QT, ceil(NT/TT)). Hits (key < Tthr[q]) compacted into cand via
// 16-lane-segment ballot aggregation (1 atomic per nonzero segment).
__global__ __launch_bounds__(256) void dist_fused_k(
    const float* __restrict__ Qm, const float* __restrict__ Tm,
    const float* __restrict__ qn, const float* __restrict__ tn,
    const int* __restrict__ labels, const unsigned* __restrict__ Tthr,
    unsigned* __restrict__ cand, int* __restrict__ ccnt, int dp)
{
  __shared__ float qs[KC][68];
  __shared__ float ts[KC][148];
  int tid = threadIdx.x;
  int qbase = blockIdx.x*QT;
  int n0 = blockIdx.y*TT;
  int kchunks = dp >> 5;
  int r0 = (tid>>4)*4, c0=(tid&15)*8;
  float acc[4][8];
  #pragma unroll
  for (int i=0;i<4;i++)
    #pragma unroll
    for (int j=0;j<8;j++) acc[i][j]=0.f;

  for (int kc=0;kc<kchunks;kc++){
    { int qq0=tid>>3, k4=(tid&7)*4;
      #pragma unroll
      for (int i=0;i<2;i++){
        int qq=qq0+i*32;
        float4 v = *(const float4*)&Qm[(size_t)(qbase+qq)*dp + kc*KC + k4];
        qs[k4+0][qq]=v.x; qs[k4+1][qq]=v.y; qs[k4+2][qq]=v.z; qs[k4+3][qq]=v.w;
      }
    }
    { int tt0=tid>>3, k4=(tid&7)*4;
      #pragma unroll
      for (int i=0;i<4;i++){
        int ttI=tt0+i*32, g=n0+ttI;
        float4 v = make_float4(0.f,0.f,0.f,0.f);
        if (g < NT) v = *(const float4*)&Tm[(size_t)g*dp + kc*KC + k4];
        int o=swz(ttI);
        ts[k4+0][o]=v.x; ts[k4+1][o]=v.y; ts[k4+2][o]=v.z; ts[k4+3][o]=v.w;
      }
    }
    __syncthreads();
    #pragma unroll 8
    for (int k=0;k<KC;k++){
      float4 a  = *(const float4*)&qs[k][r0];
      float4 b0 = *(const float4*)&ts[k][swz(c0)];
      float4 b1 = *(const float4*)&ts[k][swz(c0+4)];
      float av[4]={a.x,a.y,a.z,a.w};
      float bv[8]={b0.x,b0.y,b0.z,b0.w,b1.x,b1.y,b1.z,b1.w};
      #pragma unroll
      for (int i=0;i<4;i++)
        #pragma unroll
        for (int j=0;j<8;j++) acc[i][j] += av[i]*bv[j];
    }
    __syncthreads();
  }
  // epilogue: compare vs threshold, ballot-compact. All 64 lanes participate.
  int tl = NT - n0; if (tl > TT) tl = TT;
  bool valid = (c0 < tl);        // tl is a multiple of 8
  int lane = tid&63, seg = lane>>4, within = lane&15;
  float qnr[4]; unsigned Tq[4];
  #pragma unroll
  for (int i=0;i<4;i++){ int qr=qbase+r0+i; qnr[i]=qn[qr]; Tq[i]=Tthr[qr]; }
  float tnv[8]; unsigned labv[8];
  #pragma unroll
  for (int j=0;j<8;j++){
    int g=n0+c0+j; if (g>=NT) g=NT-1;
    tnv[j]=tn[g]; labv[j]=(unsigned)labels[g];
  }
  #pragma unroll
  for (int i=0;i<4;i++){
    int qr=qbase+r0+i;
    unsigned kk[8];
    #pragma unroll
    for (int j=0;j<8;j++){
      float d2 = fmaxf(qnr[i] - 2.f*acc[i][j] + tnv[j], 0.f);
      kk[j] = (__float_as_uint(d2)&0xFFFFFFF8u) | labv[j];
    }
    #pragma unroll
    for (int j=0;j<8;j++){
      bool hit = valid && (kk[j] < Tq[i]);
      unsigned long long m = __ballot(hit);
      unsigned segm = (unsigned)((m >> (seg*16)) & 0xFFFFull);
      int hcnt = __popc(segm);
      int base = 0;
      if (within==0 && hcnt) base = atomicAdd(&ccnt[qr], hcnt);
      base = __shfl(base, seg*16, 64);
      if (hit){
        int o = base + __popc(segm & ((1u<<within)-1u));
        if (o < CAP) cand[(size_t)qr*CAP + o] = kk[j];
      }
    }
  }
}

// ---------------- exact select over candidates + class sums -------------------
// one block per query; exact fallback recomputes distances if sampling failed
__global__ __launch_bounds__(256) void final_k(
    const unsigned* __restrict__ cand, const int* __restrict__ ccnt,
    const float* __restrict__ Qm, const float* __restrict__ Tm,
    const float* __restrict__ qn, const float* __restrict__ tn,
    const int* __restrict__ labels,
    float* __restrict__ tot, int first, int dp)
{
  __shared__ int hist[2048];
  __shared__ int part[256];
  __shared__ unsigned buf[CAP];
  __shared__ unsigned lowbuf[96];
  __shared__ float qrow[128];
  __shared__ int sB,sLob,s_cnt,s_low;
  __shared__ float s_w[9];
  int tid=threadIdx.x, q=blockIdx.x;
  int cnt=ccnt[q];
  if (tid==0){ for (int j=0;j<9;j++) s_w[j]=0.f; s_cnt=0; s_low=0; }
  __syncthreads();

#define CONTRIB(kk) do{ float d2_=__uint_as_float((kk)&0xFFFFFFF8u); \
    if (d2_>0.f){ float w_=1.0f/sqrtf(d2_); \
      atomicAdd(&s_w[8],w_); atomicAdd(&s_w[(kk)&7u],w_); } }while(0)

  unsigned T; int Krem=KNN;
  if (cnt>=KNN && cnt<=CAP){
    // ---- normal path: all top-75 keys are among the cnt candidates ----
    for (int i=tid;i<cnt;i+=256) buf[i]=cand[(size_t)q*CAP+i];
    for (int i=tid;i<2048;i+=256) hist[i]=0;
    __syncthreads();
    for (int i=tid;i<cnt;i+=256) atomicAdd(&hist[buf[i]>>21],1);
    __syncthreads();
    find_bin(hist,part,2048,Krem,tid,&sB,&sLob);
    unsigned pre=(unsigned)sB; Krem-=sLob;
    for (int i=tid;i<2048;i+=256) hist[i]=0;
    __syncthreads();
    for (int i=tid;i<cnt;i+=256){ unsigned k=buf[i]; if ((k>>21)==pre) atomicAdd(&hist[(k>>10)&0x7FFu],1); }
    __syncthreads();
    find_bin(hist,part,2048,Krem,tid,&sB,&sLob);
    pre=(pre<<11)|(unsigned)sB; Krem-=sLob;
    for (int i=tid;i<1024;i+=256) hist[i]=0;
    __syncthreads();
    for (int i=tid;i<cnt;i+=256){ unsigned k=buf[i]; if ((k>>10)==pre) atomicAdd(&hist[k&0x3FFu],1); }
    __syncthreads();
    find_bin(hist,part,1024,Krem,tid,&sB,&sLob);
    T=(pre<<10)|(unsigned)sB; Krem-=sLob;
    __syncthreads();
    for (int i=tid;i<cnt;i+=256){ unsigned k=buf[i]; if (k<T) CONTRIB(k); }
  } else {
    // ---- fallback (P ~ 1e-14 per query): exact full recompute select ----
    for (int i=tid;i<dp;i+=256) qrow[i]=Qm[(size_t)q*dp+i];
    __syncthreads();
    float qq=qn[q];
    auto KEY=[&](int t)->unsigned{
      const float* br=&Tm[(size_t)t*dp];
      float dot=0.f;
      for (int k2=0;k2<dp;k2++) dot+=qrow[k2]*br[k2];
      float d2=fmaxf(qq-2.f*dot+tn[t],0.f);
      return (__float_as_uint(d2)&0xFFFFFFF8u)|(unsigned)labels[t];
    };
    for (int i=tid;i<2048;i+=256) hist[i]=0;
    __syncthreads();
    for (int t=tid;t<NT;t+=256) atomicAdd(&hist[KEY(t)>>21],1);
    __syncthreads();
    find_bin(hist,part,2048,Krem,tid,&sB,&sLob);
    int c=hist[sB]; Krem-=sLob;
    unsigned prefix=(unsigned)sB; int shift=21;
    if (c > CAP){
      __syncthreads();
      for (int i=tid;i<2048;i+=256) hist[i]=0;
      __syncthreads();
      for (int t=tid;t<NT;t+=256){ unsigned k=KEY(t); if ((k>>21)==prefix) atomicAdd(&hist[(k>>10)&0x7FFu],1); }
      __syncthreads();
      find_bin(hist,part,2048,Krem,tid,&sB,&sLob);
      c=hist[sB]; Krem-=sLob; prefix=(prefix<<11)|(unsigned)sB; shift=10;
    }
    if (c > CAP){
      __syncthreads();
      for (int i=tid;i<1024;i+=256) hist[i]=0;
      __syncthreads();
      for (int t=tid;t<NT;t+=256){ unsigned k=KEY(t); if ((k>>10)==prefix) atomicAdd(&hist[k&0x3FFu],1); }
      __syncthreads();
      find_bin(hist,part,1024,Krem,tid,&sB,&sLob);
      c=hist[sB]; Krem-=sLob; prefix=(prefix<<10)|(unsigned)sB; shift=0;
    }
    if (c <= CAP){
      for (int t=tid;t<NT;t+=256){
        unsigned k=KEY(t); unsigned pp=k>>shift;
        if (pp==prefix){ int j=atomicAdd(&s_cnt,1); if (j<CAP) buf[j]=k; }
        else if (pp<prefix){ int j=atomicAdd(&s_low,1); if (j<96) lowbuf[j]=k; }
      }
      __syncthreads();
      int sh=shift;
      while (sh>0){
        int nsh=(sh==21)?10:0;
        int nb=1<<(sh-nsh);
        __syncthreads();
        for (int i=tid;i<nb;i+=256) hist[i]=0;
        __syncthreads();
        int cc=s_cnt;
        for (int i=tid;i<cc;i+=256) atomicAdd(&hist[(buf[i]>>nsh)&(unsigned)(nb-1)],1);
        __syncthreads();
        find_bin(hist,part,nb,Krem,tid,&sB,&sLob);
        Krem-=sLob; prefix=(prefix<<(sh-nsh))|(unsigned)sB; sh=nsh;
      }
      T=prefix;
      __syncthreads();
      int lowc=s_low, cc=s_cnt;
      for (int i=tid;i<lowc;i+=256){ unsigned k=lowbuf[i]; CONTRIB(k); }
      for (int i=tid;i<cc;i+=256){ unsigned k=buf[i]; if (k<T) CONTRIB(k); }
    } else {
      T=prefix;  // shift==0: mass duplicates at T
      for (int t=tid;t<NT;t+=256){ unsigned k=KEY(t); if (k<T) CONTRIB(k); }
    }
  }
  __syncthreads();
  if (tid==0){
    // remaining Krem neighbors all have key == T (same truncated d2 AND label)
    float d2=__uint_as_float(T&0xFFFFFFF8u);
    float w=(d2>0.f)?(1.0f/sqrtf(d2)):0.f;
    s_w[8] += (float)Krem*w;
    s_w[T&7u] += (float)Krem*w;
  }
  __syncthreads();
  if (tid<8){
    float contrib = s_w[8]-s_w[tid];
    size_t o=(size_t)q*NL+tid;
    tot[o] = first ? contrib : tot[o]+contrib;
  }
#undef CONTRIB
}

// ---------------- empirical p-values ------------------------------------------
__global__ void pvalue_k(const float* __restrict__ tot, const float* __restrict__ cali,
                         float* __restrict__ out){
  __shared__ float t8[NL];
  __shared__ int part[4][NL];
  int tid=threadIdx.x, q=blockIdx.x;
  if (tid<NL) t8[tid]=tot[(size_t)q*NL+tid];
  __syncthreads();
  float th[NL];
  #pragma unroll
  for (int c=0;c<NL;c++) th[c]=t8[c];
  int cnt[NL];
  #pragma unroll
  for (int c=0;c<NL;c++) cnt[c]=0;
  for (int i=tid;i<NCALI;i+=256){
    float v=cali[i];
    #pragma unroll
    for (int c=0;c<NL;c++) cnt[c] += (v>=th[c]) ? 1 : 0;
  }
  #pragma unroll
  for (int c=0;c<NL;c++){
    #pragma unroll
    for (int off=32;off>0;off>>=1) cnt[c]+=__shfl_down(cnt[c],off,64);
  }
  if ((tid&63)==0){
    #pragma unroll
    for (int c=0;c<NL;c++) part[tid>>6][c]=cnt[c];
  }
  __syncthreads();
  if (tid<NL){
    int s=part[0][tid]+part[1][tid]+part[2][tid]+part[3][tid];
    out[(size_t)q*NL+tid] = (float)s / 10000.f;
  }
}

extern "C" void kernel_launch(void* const* d_in, const int* in_sizes, int n_in,
                              void* d_out, int out_size, void* d_ws, size_t ws_size,
                              hipStream_t stream) {
  const float* x   = (const float*)d_in[0];
  const float* txr = (const float*)d_in[1];
  const int*   lbl = (const int*)  d_in[2];
  const float* cal = (const float*)d_in[3];
  const float* W1  = (const float*)d_in[4];
  const float* b1  = (const float*)d_in[5];
  const float* W2  = (const float*)d_in[6];
  const float* b2  = (const float*)d_in[7];
  const float* W3  = (const float*)d_in[8];
  const float* b3  = (const float*)d_in[9];
  const float* W4  = (const float*)d_in[10];
  const float* b4  = (const float*)d_in[11];
  float* out = (float*)d_out;
  float* ws  = (float*)d_ws;

  size_t off=0;
  float* xq0=ws+off; off+=(size_t)NB*96;
  float* xq1=ws+off; off+=(size_t)NB*128;
  float* xq2=ws+off; off+=(size_t)NB*128;
  float* xq3=ws+off; off+=(size_t)NB*128;
  float* xq4=ws+off; off+=(size_t)NB*32;
  float* tbA=ws+off; off+=(size_t)NT*128;
  float* tbB=ws+off; off+=(size_t)NT*128;
  float* tb4=ws+off; off+=(size_t)NT*32;
  float* qnb=ws+off; off+=(size_t)5*NB;
  float* tnb=ws+off; off+=(size_t)NT;
  float* Tsub=ws+off; off+=(size_t)NSUB*128;
  float* tnsub=ws+off; off+=(size_t)NSUB;
  float* tot=ws+off; off+=(size_t)NB*NL;
  unsigned* skeys=(unsigned*)(ws+off); off+=(size_t)NB*NSUB;
  unsigned* sT=(unsigned*)(ws+off);    off+=NB;
  int* ccnt=(int*)(ws+off);            off+=NB;
  unsigned* cand=(unsigned*)(ws+off);  off+=(size_t)NB*CAP;   // ~95MB total

  // query features; layer-0 features at stride 96
  pad_copy_k<<<(NB*96+255)/256,256,0,stream>>>(x, xq0, NB, 83, 96);
  pad_copy_k<<<((size_t)NT*96+255)/256,256,0,stream>>>(txr, tbA, NT, 83, 96);
  mlp_gemm_k<<<(NB+127)/128,256,0,stream>>>(xq0,96,3,W1,83,b1,xq1,NB);
  mlp_gemm_k<<<(NB+127)/128,256,0,stream>>>(xq1,128,4,W2,128,b2,xq2,NB);
  mlp_gemm_k<<<(NB+127)/128,256,0,stream>>>(xq2,128,4,W3,128,b3,xq3,NB);
  mlp8_k<<<(NB+31)/32,256,0,stream>>>(xq3,W4,b4,xq4,NB);
  softmax_k<<<(NB+255)/256,256,0,stream>>>(xq4,NB);
  rownorm_k<<<(NB+3)/4,256,0,stream>>>(xq0,qnb+0*NB,NB,96);
  rownorm_k<<<(NB+3)/4,256,0,stream>>>(xq1,qnb+1*NB,NB,128);
  rownorm_k<<<(NB+3)/4,256,0,stream>>>(xq2,qnb+2*NB,NB,128);
  rownorm_k<<<(NB+3)/4,256,0,stream>>>(xq3,qnb+3*NB,NB,128);
  rownorm_k<<<(NB+3)/4,256,0,stream>>>(xq4,qnb+4*NB,NB,32);

  auto knn_layer = [&](const float* Qm, const float* Bank, const float* qnl,
                       int dp, int first){
    rownorm_k<<<(NT+3)/4,256,0,stream>>>(Bank,tnb,NT,dp);
    sub_gather_k<<<(NSUB*dp+NSUB+255)/256,256,0,stream>>>(Bank,tnb,Tsub,tnsub,dp);
    dist_key_k<<<dim3(NB/QT,NSUB/TT),256,0,stream>>>(Qm,Tsub,qnl,tnsub,lbl,skeys,dp,NSUB);
    sel64_k<<<NB,256,0,stream>>>(skeys,sT,ccnt);
    dist_fused_k<<<dim3(NB/QT,(NT+TT-1)/TT),256,0,stream>>>(
        Qm,Bank,qnl,tnb,lbl,sT,cand,ccnt,dp);
    final_k<<<NB,256,0,stream>>>(cand,ccnt,Qm,Bank,qnl,tnb,lbl,tot,first,dp);
  };

  knn_layer(xq0, tbA, qnb+0*NB, 96, 1);
  mlp_gemm_k<<<(NT+127)/128,256,0,stream>>>(tbA,96,3,W1,83,b1,tbB,NT);
  knn_layer(xq1, tbB, qnb+1*NB, 128, 0);
  mlp_gemm_k<<<(NT+127)/128,256,0,stream>>>(tbB,128,4,W2,128,b2,tbA,NT);
  knn_layer(xq2, tbA, qnb+2*NB, 128, 0);
  mlp_gemm_k<<<(NT+127)/128,256,0,stream>>>(tbA,128,4,W3,128,b3,tbB,NT);
  knn_layer(xq3, tbB, qnb+3*NB, 128, 0);
  mlp8_k<<<(NT+31)/32,256,0,stream>>>(tbB,W4,b4,tb4,NT);
  softmax_k<<<(NT+255)/256,256,0,stream>>>(tb4,NT);
  knn_layer(xq4, tb4, qnb+4*NB, 32, 0);

  pvalue_k<<<NB,256,0,stream>>>(tot,cal,out);
}

// Round 5
// 1690.018 us; speedup vs baseline: 5.0196x; 1.7368x over previous
//
#include <hip/hip_runtime.h>
#include <math.h>

#define KNN 75
#define NL 8
#define NB 1024
#define NT 50000
#define NCALI 10000
#define KC 32
#define QT 64
#define TT 128
#define NTB 391       // ceil(NT/TT)
#define SLOTS 16      // per (q, t-block) slab: [count, up to 15 hit keys]
#define CAP 6144      // candidate buffer per query
#define NSUB 2048     // sampled train points for threshold
#define SSTRIDE 24
#define SOFF 11       // 11 + 24*2047 = 49139 < 50000
#define RSEL 32       // sample rank -> expected |{k < T}| ~ 781, lambda/slab ~ 2

__device__ __forceinline__ int swz(int c){ return c + ((c>>5)<<2); }

// ---------------- pad copy (zero-fill pad cols every call: ws is poisoned) ----
__global__ void pad_copy_k(const float* __restrict__ in, float* __restrict__ out,
                           int M, int Din, int Dout){
  int idx = blockIdx.x*256 + threadIdx.x;
  if (idx >= M*Dout) return;
  int r = idx / Dout, c = idx - r*Dout;
  out[idx] = (c < Din) ? in[r*Din + c] : 0.f;
}

// ---------------- MLP GEMM: Out[M][128] = relu(A[M][lda] @ W[kreal][128] + b) --
__global__ __launch_bounds__(256) void mlp_gemm_k(
    const float* __restrict__ A, int lda, int kchunks,
    const float* __restrict__ W, int kreal,
    const float* __restrict__ bias,
    float* __restrict__ Out, int M)
{
  __shared__ float As[KC][132];
  __shared__ float Bs[KC][148];
  int tid = threadIdx.x;
  int r0 = (tid>>4)*8, c0 = (tid&15)*8;
  int rowBase = blockIdx.x*128;
  float acc[8][8];
  #pragma unroll
  for (int i=0;i<8;i++)
    #pragma unroll
    for (int j=0;j<8;j++) acc[i][j]=0.f;

  for (int kc=0;kc<kchunks;kc++){
    { int rr = tid>>3, k4=(tid&7)*4;
      #pragma unroll
      for (int i=0;i<4;i++){
        int row = rr + i*32, gr = rowBase + row;
        float4 v = make_float4(0.f,0.f,0.f,0.f);
        if (gr < M) v = *(const float4*)&A[(size_t)gr*lda + kc*KC + k4];
        As[k4+0][row]=v.x; As[k4+1][row]=v.y; As[k4+2][row]=v.z; As[k4+3][row]=v.w;
      }
    }
    { int kk=tid>>5, c4=(tid&31)*4;
      #pragma unroll
      for (int i=0;i<4;i++){
        int k = kk + i*8, gk = kc*KC + k;
        float4 v = make_float4(0.f,0.f,0.f,0.f);
        if (gk < kreal) v = *(const float4*)&W[(size_t)gk*128 + c4];
        *(float4*)&Bs[k][swz(c4)] = v;
      }
    }
    __syncthreads();
    #pragma unroll 4
    for (int k=0;k<KC;k++){
      float4 a0 = *(const float4*)&As[k][r0];
      float4 a1 = *(const float4*)&As[k][r0+4];
      float4 b0 = *(const float4*)&Bs[k][swz(c0)];
      float4 b1 = *(const float4*)&Bs[k][swz(c0+4)];
      float av[8] = {a0.x,a0.y,a0.z,a0.w,a1.x,a1.y,a1.z,a1.w};
      float bv[8] = {b0.x,b0.y,b0.z,b0.w,b1.x,b1.y,b1.z,b1.w};
      #pragma unroll
      for (int i=0;i<8;i++)
        #pragma unroll
        for (int j=0;j<8;j++) acc[i][j] += av[i]*bv[j];
    }
    __syncthreads();
  }
  float bb[8];
  #pragma unroll
  for (int j=0;j<8;j++) bb[j]=bias[c0+j];
  #pragma unroll
  for (int i=0;i<8;i++){
    int gr = rowBase + r0 + i;
    if (gr < M){
      float o[8];
      #pragma unroll
      for (int j=0;j<8;j++){ float v=acc[i][j]+bb[j]; o[j]=v>0.f?v:0.f; }
      *(float4*)&Out[(size_t)gr*128 + c0]   = make_float4(o[0],o[1],o[2],o[3]);
      *(float4*)&Out[(size_t)gr*128 + c0+4] = make_float4(o[4],o[5],o[6],o[7]);
    }
  }
}

// ---------------- last layer: logits[M][8] into stride-32 rows ----------------
__global__ void mlp8_k(const float* __restrict__ A, const float* __restrict__ W4,
                       const float* __restrict__ b4, float* __restrict__ Out, int M){
  __shared__ float Ws[128*8];
  int tid = threadIdx.x;
  for (int i=tid;i<1024;i+=256) Ws[i]=W4[i];
  __syncthreads();
  int r = blockIdx.x*32 + (tid>>3), c = tid&7;
  if (r >= M) return;
  const float* a = &A[(size_t)r*128];
  float acc = b4[c];
  #pragma unroll 16
  for (int k=0;k<128;k++) acc += a[k]*Ws[k*8+c];
  Out[(size_t)r*32 + c] = acc;
}

// ---------------- softmax over 8 logits, zero cols 8..31 ----------------------
__global__ void softmax_k(float* __restrict__ X, int M){
  int r = blockIdx.x*256 + threadIdx.x;
  if (r >= M) return;
  float* p = &X[(size_t)r*32];
  float v[8], m=-1e30f;
  #pragma unroll
  for (int j=0;j<8;j++){ v[j]=p[j]; m = v[j]>m ? v[j] : m; }
  float s=0.f;
  #pragma unroll
  for (int j=0;j<8;j++){ v[j]=__expf(v[j]-m); s+=v[j]; }
  float inv=1.f/s;
  #pragma unroll
  for (int j=0;j<8;j++) p[j]=v[j]*inv;
  #pragma unroll
  for (int j=8;j<32;j++) p[j]=0.f;
}

// ---------------- row squared-norms (one wave per row) ------------------------
__global__ void rownorm_k(const float* __restrict__ X, float* __restrict__ out,
                          int M, int dp){
  int w = threadIdx.x>>6, lane = threadIdx.x&63;
  int row = blockIdx.x*4 + w;
  if (row >= M) return;
  float s=0.f;
  for (int c=lane;c<dp;c+=64){ float v=X[(size_t)row*dp+c]; s+=v*v; }
  #pragma unroll
  for (int off=32;off>0;off>>=1) s += __shfl_down(s, off, 64);
  if (lane==0) out[row]=s;
}

// ---------------- gather sampled subset bank + its norms ----------------------
__global__ void sub_gather_k(const float* __restrict__ Bank, const float* __restrict__ tnb,
                             float* __restrict__ Tsub, float* __restrict__ tnsub, int dp){
  int idx = blockIdx.x*256 + threadIdx.x;
  int total = NSUB*dp;
  if (idx < total){
    int s = idx/dp, c = idx - s*dp;
    Tsub[idx] = Bank[(size_t)(s*SSTRIDE+SOFF)*dp + c];
  } else if (idx < total + NSUB){
    int s = idx - total;
    tnsub[s] = tnb[s*SSTRIDE+SOFF];
  }
}

// ---------------- subset distance GEMM -> packed keys -------------------------
// grid (NB/QT, nt/TT); labels here index subset rows (approximate) — fine,
// keys are only used to pick a threshold VALUE.
__global__ __launch_bounds__(256) void dist_key_k(
    const float* __restrict__ Qm, const float* __restrict__ Tm,
    const float* __restrict__ qn, const float* __restrict__ tn,
    const int* __restrict__ labels, unsigned* __restrict__ keys, int dp, int nt)
{
  __shared__ float qs[KC][68];
  __shared__ float ts[KC][148];
  int tid = threadIdx.x;
  int qbase = blockIdx.x*QT;
  int n0 = blockIdx.y*TT;
  int kchunks = dp >> 5;
  int r0 = (tid>>4)*4, c0=(tid&15)*8;
  float acc[4][8];
  #pragma unroll
  for (int i=0;i<4;i++)
    #pragma unroll
    for (int j=0;j<8;j++) acc[i][j]=0.f;

  for (int kc=0;kc<kchunks;kc++){
    { int qq0=tid>>3, k4=(tid&7)*4;
      #pragma unroll
      for (int i=0;i<2;i++){
        int qq=qq0+i*32;
        float4 v = *(const float4*)&Qm[(size_t)(qbase+qq)*dp + kc*KC + k4];
        qs[k4+0][qq]=v.x; qs[k4+1][qq]=v.y; qs[k4+2][qq]=v.z; qs[k4+3][qq]=v.w;
      }
    }
    { int tt0=tid>>3, k4=(tid&7)*4;
      #pragma unroll
      for (int i=0;i<4;i++){
        int ttI=tt0+i*32, g=n0+ttI;
        float4 v = make_float4(0.f,0.f,0.f,0.f);
        if (g < nt) v = *(const float4*)&Tm[(size_t)g*dp + kc*KC + k4];
        int o=swz(ttI);
        ts[k4+0][o]=v.x; ts[k4+1][o]=v.y; ts[k4+2][o]=v.z; ts[k4+3][o]=v.w;
      }
    }
    __syncthreads();
    #pragma unroll 8
    for (int k=0;k<KC;k++){
      float4 a  = *(const float4*)&qs[k][r0];
      float4 b0 = *(const float4*)&ts[k][swz(c0)];
      float4 b1 = *(const float4*)&ts[k][swz(c0+4)];
      float av[4]={a.x,a.y,a.z,a.w};
      float bv[8]={b0.x,b0.y,b0.z,b0.w,b1.x,b1.y,b1.z,b1.w};
      #pragma unroll
      for (int i=0;i<4;i++)
        #pragma unroll
        for (int j=0;j<8;j++) acc[i][j] += av[i]*bv[j];
    }
    __syncthreads();
  }
  int tl = nt - n0; if (tl > TT) tl = TT;
  if (c0 < tl){
    float qnr[4];
    #pragma unroll
    for (int i=0;i<4;i++) qnr[i]=qn[qbase+r0+i];
    float tnv[8]; unsigned labv[8];
    #pragma unroll
    for (int j=0;j<8;j++){ int g=n0+c0+j; tnv[j]=tn[g]; labv[j]=(unsigned)labels[g]; }
    #pragma unroll
    for (int i=0;i<4;i++){
      unsigned kk[8];
      #pragma unroll
      for (int j=0;j<8;j++){
        float d2 = fmaxf(qnr[i] - 2.f*acc[i][j] + tnv[j], 0.f);
        kk[j] = (__float_as_uint(d2)&0xFFFFFFF8u) | labv[j];
      }
      unsigned* dst = &keys[(size_t)(qbase+r0+i)*nt + n0+c0];
      *(uint4*)dst     = make_uint4(kk[0],kk[1],kk[2],kk[3]);
      *(uint4*)(dst+4) = make_uint4(kk[4],kk[5],kk[6],kk[7]);
    }
  }
}

// ---------------- scan helper: find bin containing rank Krem ------------------
__device__ __forceinline__ void find_bin(int* hist, int* part, int nb, int Krem,
                                         int tid, int* s_B, int* s_lob){
  int ch = nb>>8;
  int s=0;
  for (int b=tid*ch;b<tid*ch+ch;b++) s+=hist[b];
  part[tid]=s;
  __syncthreads();
  if (tid==0){
    int cum=0, B=nb-1, lob=0;
    for (int t=0;t<256;t++){
      if (cum+part[t] >= Krem){
        lob=cum;
        for (int b=t*ch;b<t*ch+ch;b++){
          if (lob+hist[b]>=Krem){ B=b; break; }
          lob+=hist[b];
        }
        break;
      }
      cum+=part[t];
    }
    *s_B=B; *s_lob=lob;
  }
  __syncthreads();
}

// ---------------- per-query threshold: exact RSEL-th smallest sample key ------
__global__ __launch_bounds__(256) void sel64_k(const unsigned* __restrict__ skeys,
                                               unsigned* __restrict__ Tthr){
  __shared__ unsigned buf[NSUB];
  __shared__ int hist[2048];
  __shared__ int part[256];
  __shared__ int sB, sLob;
  int tid=threadIdx.x, q=blockIdx.x;
  for (int i=tid;i<NSUB;i+=256) buf[i]=skeys[(size_t)q*NSUB+i];
  int Krem=RSEL;
  for (int i=tid;i<2048;i+=256) hist[i]=0;
  __syncthreads();
  for (int i=tid;i<NSUB;i+=256) atomicAdd(&hist[buf[i]>>21],1);
  __syncthreads();
  find_bin(hist,part,2048,Krem,tid,&sB,&sLob);
  unsigned pre=(unsigned)sB; Krem-=sLob;
  for (int i=tid;i<2048;i+=256) hist[i]=0;
  __syncthreads();
  for (int i=tid;i<NSUB;i+=256){ unsigned k=buf[i]; if ((k>>21)==pre) atomicAdd(&hist[(k>>10)&0x7FFu],1); }
  __syncthreads();
  find_bin(hist,part,2048,Krem,tid,&sB,&sLob);
  pre=(pre<<11)|(unsigned)sB; Krem-=sLob;
  for (int i=tid;i<1024;i+=256) hist[i]=0;
  __syncthreads();
  for (int i=tid;i<NSUB;i+=256){ unsigned k=buf[i]; if ((k>>10)==pre) atomicAdd(&hist[k&0x3FFu],1); }
  __syncthreads();
  find_bin(hist,part,1024,Krem,tid,&sB,&sLob);
  if (tid==0) Tthr[q]=(pre<<10)|(unsigned)sB;
}

// ---------------- fused 128x128 distance GEMM + private-slab compaction -------
// grid (NB/128, NTB). Hits staged in LDS, dumped as full-line private slabs:
// slab[q][tb] = [count, hit keys...] (SLOTS words). No global atomics at all.
__global__ __launch_bounds__(256) void dist_fused2_k(
    const float* __restrict__ Qm, const float* __restrict__ Tm,
    const float* __restrict__ qn, const float* __restrict__ tn,
    const int* __restrict__ labels, const unsigned* __restrict__ Tthr,
    unsigned* __restrict__ slab, int dp)
{
  __shared__ float qs[KC][132];
  __shared__ float ts[KC][148];
  __shared__ unsigned hitbuf[128][SLOTS];
  __shared__ int hcnt[128];
  int tid = threadIdx.x;
  int qbase = blockIdx.x*128;
  int n0 = blockIdx.y*TT;
  int kchunks = dp >> 5;
  int r0 = (tid>>4)*8, c0 = (tid&15)*8;
  float acc[8][8];
  #pragma unroll
  for (int i=0;i<8;i++)
    #pragma unroll
    for (int j=0;j<8;j++) acc[i][j]=0.f;

  for (int kc=0;kc<kchunks;kc++){
    { int rr = tid>>3, k4=(tid&7)*4;
      #pragma unroll
      for (int i=0;i<4;i++){
        int row = rr + i*32;
        float4 v = *(const float4*)&Qm[(size_t)(qbase+row)*dp + kc*KC + k4];
        qs[k4+0][row]=v.x; qs[k4+1][row]=v.y; qs[k4+2][row]=v.z; qs[k4+3][row]=v.w;
      }
    }
    { int tt0 = tid>>3, k4=(tid&7)*4;
      #pragma unroll
      for (int i=0;i<4;i++){
        int ttI=tt0+i*32, g=n0+ttI;
        float4 v = make_float4(0.f,0.f,0.f,0.f);
        if (g < NT) v = *(const float4*)&Tm[(size_t)g*dp + kc*KC + k4];
        int o=swz(ttI);
        ts[k4+0][o]=v.x; ts[k4+1][o]=v.y; ts[k4+2][o]=v.z; ts[k4+3][o]=v.w;
      }
    }
    __syncthreads();
    #pragma unroll 4
    for (int k=0;k<KC;k++){
      float4 a0 = *(const float4*)&qs[k][r0];
      float4 a1 = *(const float4*)&qs[k][r0+4];
      float4 b0 = *(const float4*)&ts[k][swz(c0)];
      float4 b1 = *(const float4*)&ts[k][swz(c0+4)];
      float av[8] = {a0.x,a0.y,a0.z,a0.w,a1.x,a1.y,a1.z,a1.w};
      float bv[8] = {b0.x,b0.y,b0.z,b0.w,b1.x,b1.y,b1.z,b1.w};
      #pragma unroll
      for (int i=0;i<8;i++)
        #pragma unroll
        for (int j=0;j<8;j++) acc[i][j] += av[i]*bv[j];
    }
    __syncthreads();
  }
  // epilogue: compare vs per-query threshold, compact into LDS slabs
  if (tid<128) hcnt[tid]=0;
  __syncthreads();
  int tl = NT - n0; if (tl > TT) tl = TT;
  if (c0 < tl){   // tl is a multiple of 8
    float tnv[8]; unsigned labv[8];
    #pragma unroll
    for (int j=0;j<8;j++){ int g=n0+c0+j; tnv[j]=tn[g]; labv[j]=(unsigned)labels[g]; }
    #pragma unroll
    for (int i=0;i<8;i++){
      int qr=qbase+r0+i;
      float qnr=qn[qr];
      unsigned Tq=Tthr[qr];
      #pragma unroll
      for (int j=0;j<8;j++){
        float d2 = fmaxf(qnr - 2.f*acc[i][j] + tnv[j], 0.f);
        unsigned key = (__float_as_uint(d2)&0xFFFFFFF8u) | labv[j];
        if (key < Tq){
          int idx = atomicAdd(&hcnt[r0+i], 1);
          if (idx < SLOTS-1) hitbuf[r0+i][1+idx] = key;
        }
      }
    }
  }
  __syncthreads();
  if (tid<128) hitbuf[tid][0]=(unsigned)hcnt[tid];
  __syncthreads();
  // dump 128 slabs x SLOTS words as coalesced full-line uint4 stores
  #pragma unroll
  for (int rep=0; rep<(128*SLOTS/4)/256; rep++){
    int idx = rep*256 + tid;
    int q = idx>>2, sub = (idx&3)*4;
    uint4 v = *(uint4*)&hitbuf[q][sub];
    *(uint4*)&slab[((size_t)(qbase+q)*NTB + blockIdx.y)*SLOTS + sub] = v;
  }
}

// ---------------- gather slabs, exact radix select + class sums ---------------
// one block per query; exact fallback recomputes distances if sampling failed
__global__ __launch_bounds__(256) void final_k(
    const unsigned* __restrict__ slab,
    const float* __restrict__ Qm, const float* __restrict__ Tm,
    const float* __restrict__ qn, const float* __restrict__ tn,
    const int* __restrict__ labels,
    float* __restrict__ tot, int first, int dp)
{
  __shared__ int hist[2048];
  __shared__ int part[256];
  __shared__ unsigned buf[CAP];
  __shared__ unsigned lowbuf[96];
  __shared__ float qrow[128];
  __shared__ int sB,sLob,s_cnt,s_low,s_bad;
  __shared__ float s_w[9];
  int tid=threadIdx.x, q=blockIdx.x;
  if (tid==0){ for (int j=0;j<9;j++) s_w[j]=0.f; s_cnt=0; s_low=0; s_bad=0; }
  __syncthreads();

  // gather candidates from private slabs
  const unsigned* sq = slab + (size_t)q*NTB*SLOTS;
  for (int sidx=tid; sidx<NTB; sidx+=256){
    const unsigned* s = sq + (size_t)sidx*SLOTS;
    uint4 a = *(const uint4*)s;
    unsigned cnt = a.x;
    if (cnt > SLOTS-1){ s_bad=1; continue; }
    if (!cnt) continue;
    int base = atomicAdd(&s_cnt, (int)cnt);
    if (base + (int)cnt <= CAP){
      buf[base] = a.y;
      if (cnt>=2) buf[base+1] = a.z;
      if (cnt>=3) buf[base+2] = a.w;
      for (unsigned w=4; w<=cnt; w++) buf[base+w-1] = s[w];
    }
  }
  __syncthreads();
  int total = s_cnt;
  int bad = s_bad;

#define CONTRIB(kk) do{ float d2_=__uint_as_float((kk)&0xFFFFFFF8u); \
    if (d2_>0.f){ float w_=1.0f/sqrtf(d2_); \
      atomicAdd(&s_w[8],w_); atomicAdd(&s_w[(kk)&7u],w_); } }while(0)

  unsigned T; int Krem=KNN;
  if (!bad && total>=KNN && total<=CAP){
    // ---- normal path: exact top-75 among the `total` candidates ----
    for (int i=tid;i<2048;i+=256) hist[i]=0;
    __syncthreads();
    for (int i=tid;i<total;i+=256) atomicAdd(&hist[buf[i]>>21],1);
    __syncthreads();
    find_bin(hist,part,2048,Krem,tid,&sB,&sLob);
    unsigned pre=(unsigned)sB; Krem-=sLob;
    for (int i=tid;i<2048;i+=256) hist[i]=0;
    __syncthreads();
    for (int i=tid;i<total;i+=256){ unsigned k=buf[i]; if ((k>>21)==pre) atomicAdd(&hist[(k>>10)&0x7FFu],1); }
    __syncthreads();
    find_bin(hist,part,2048,Krem,tid,&sB,&sLob);
    pre=(pre<<11)|(unsigned)sB; Krem-=sLob;
    for (int i=tid;i<1024;i+=256) hist[i]=0;
    __syncthreads();
    for (int i=tid;i<total;i+=256){ unsigned k=buf[i]; if ((k>>10)==pre) atomicAdd(&hist[k&0x3FFu],1); }
    __syncthreads();
    find_bin(hist,part,1024,Krem,tid,&sB,&sLob);
    T=(pre<<10)|(unsigned)sB; Krem-=sLob;
    __syncthreads();
    for (int i=tid;i<total;i+=256){ unsigned k=buf[i]; if (k<T) CONTRIB(k); }
  } else {
    // ---- fallback (astronomically rare): exact full recompute select ----
    if (tid==0) s_cnt=0;
    for (int i=tid;i<dp;i+=256) qrow[i]=Qm[(size_t)q*dp+i];
    __syncthreads();
    float qq=qn[q];
    auto KEY=[&](int t)->unsigned{
      const float* br=&Tm[(size_t)t*dp];
      float dot=0.f;
      for (int k2=0;k2<dp;k2++) dot+=qrow[k2]*br[k2];
      float d2=fmaxf(qq-2.f*dot+tn[t],0.f);
      return (__float_as_uint(d2)&0xFFFFFFF8u)|(unsigned)labels[t];
    };
    for (int i=tid;i<2048;i+=256) hist[i]=0;
    __syncthreads();
    for (int t=tid;t<NT;t+=256) atomicAdd(&hist[KEY(t)>>21],1);
    __syncthreads();
    find_bin(hist,part,2048,Krem,tid,&sB,&sLob);
    int c=hist[sB]; Krem-=sLob;
    unsigned prefix=(unsigned)sB; int shift=21;
    if (c > CAP){
      __syncthreads();
      for (int i=tid;i<2048;i+=256) hist[i]=0;
      __syncthreads();
      for (int t=tid;t<NT;t+=256){ unsigned k=KEY(t); if ((k>>21)==prefix) atomicAdd(&hist[(k>>10)&0x7FFu],1); }
      __syncthreads();
      find_bin(hist,part,2048,Krem,tid,&sB,&sLob);
      c=hist[sB]; Krem-=sLob; prefix=(prefix<<11)|(unsigned)sB; shift=10;
    }
    if (c > CAP){
      __syncthreads();
      for (int i=tid;i<1024;i+=256) hist[i]=0;
      __syncthreads();
      for (int t=tid;t<NT;t+=256){ unsigned k=KEY(t); if ((k>>10)==prefix) atomicAdd(&hist[k&0x3FFu],1); }
      __syncthreads();
      find_bin(hist,part,1024,Krem,tid,&sB,&sLob);
      c=hist[sB]; Krem-=sLob; prefix=(prefix<<10)|(unsigned)sB; shift=0;
    }
    if (c <= CAP){
      for (int t=tid;t<NT;t+=256){
        unsigned k=KEY(t); unsigned pp=k>>shift;
        if (pp==prefix){ int j=atomicAdd(&s_cnt,1); if (j<CAP) buf[j]=k; }
        else if (pp<prefix){ int j=atomicAdd(&s_low,1); if (j<96) lowbuf[j]=k; }
      }
      __syncthreads();
      int sh=shift;
      while (sh>0){
        int nsh=(sh==21)?10:0;
        int nb=1<<(sh-nsh);
        __syncthreads();
        for (int i=tid;i<nb;i+=256) hist[i]=0;
        __syncthreads();
        int cc=s_cnt;
        for (int i=tid;i<cc;i+=256) atomicAdd(&hist[(buf[i]>>nsh)&(unsigned)(nb-1)],1);
        __syncthreads();
        find_bin(hist,part,nb,Krem,tid,&sB,&sLob);
        Krem-=sLob; prefix=(prefix<<(sh-nsh))|(unsigned)sB; sh=nsh;
      }
      T=prefix;
      __syncthreads();
      int lowc=s_low, cc=s_cnt;
      for (int i=tid;i<lowc;i+=256){ unsigned k=lowbuf[i]; CONTRIB(k); }
      for (int i=tid;i<cc;i+=256){ unsigned k=buf[i]; if (k<T) CONTRIB(k); }
    } else {
      T=prefix;  // shift==0: mass duplicates at T
      for (int t=tid;t<NT;t+=256){ unsigned k=KEY(t); if (k<T) CONTRIB(k); }
    }
  }
  __syncthreads();
  if (tid==0){
    // remaining Krem neighbors all have key == T (same truncated d2 AND label)
    float d2=__uint_as_float(T&0xFFFFFFF8u);
    float w=(d2>0.f)?(1.0f/sqrtf(d2)):0.f;
    s_w[8] += (float)Krem*w;
    s_w[T&7u] += (float)Krem*w;
  }
  __syncthreads();
  if (tid<8){
    float contrib = s_w[8]-s_w[tid];
    size_t o=(size_t)q*NL+tid;
    tot[o] = first ? contrib : tot[o]+contrib;
  }
#undef CONTRIB
}

// ---------------- empirical p-values ------------------------------------------
__global__ void pvalue_k(const float* __restrict__ tot, const float* __restrict__ cali,
                         float* __restrict__ out){
  __shared__ float t8[NL];
  __shared__ int part[4][NL];
  int tid=threadIdx.x, q=blockIdx.x;
  if (tid<NL) t8[tid]=tot[(size_t)q*NL+tid];
  __syncthreads();
  float th[NL];
  #pragma unroll
  for (int c=0;c<NL;c++) th[c]=t8[c];
  int cnt[NL];
  #pragma unroll
  for (int c=0;c<NL;c++) cnt[c]=0;
  for (int i=tid;i<NCALI;i+=256){
    float v=cali[i];
    #pragma unroll
    for (int c=0;c<NL;c++) cnt[c] += (v>=th[c]) ? 1 : 0;
  }
  #pragma unroll
  for (int c=0;c<NL;c++){
    #pragma unroll
    for (int off=32;off>0;off>>=1) cnt[c]+=__shfl_down(cnt[c],off,64);
  }
  if ((tid&63)==0){
    #pragma unroll
    for (int c=0;c<NL;c++) part[tid>>6][c]=cnt[c];
  }
  __syncthreads();
  if (tid<NL){
    int s=part[0][tid]+part[1][tid]+part[2][tid]+part[3][tid];
    out[(size_t)q*NL+tid] = (float)s / 10000.f;
  }
}

extern "C" void kernel_launch(void* const* d_in, const int* in_sizes, int n_in,
                              void* d_out, int out_size, void* d_ws, size_t ws_size,
                              hipStream_t stream) {
  const float* x   = (const float*)d_in[0];
  const float* txr = (const float*)d_in[1];
  const int*   lbl = (const int*)  d_in[2];
  const float* cal = (const float*)d_in[3];
  const float* W1  = (const float*)d_in[4];
  const float* b1  = (const float*)d_in[5];
  const float* W2  = (const float*)d_in[6];
  const float* b2  = (const float*)d_in[7];
  const float* W3  = (const float*)d_in[8];
  const float* b3  = (const float*)d_in[9];
  const float* W4  = (const float*)d_in[10];
  const float* b4  = (const float*)d_in[11];
  float* out = (float*)d_out;
  float* ws  = (float*)d_ws;

  size_t off=0;
  float* xq0=ws+off; off+=(size_t)NB*96;
  float* xq1=ws+off; off+=(size_t)NB*128;
  float* xq2=ws+off; off+=(size_t)NB*128;
  float* xq3=ws+off; off+=(size_t)NB*128;
  float* xq4=ws+off; off+=(size_t)NB*32;
  float* tbA=ws+off; off+=(size_t)NT*128;
  float* tbB=ws+off; off+=(size_t)NT*128;
  float* tb4=ws+off; off+=(size_t)NT*32;
  float* qnb=ws+off; off+=(size_t)5*NB;
  float* tnb=ws+off; off+=(size_t)NT;
  float* Tsub=ws+off; off+=(size_t)NSUB*128;
  float* tnsub=ws+off; off+=(size_t)NSUB;
  float* tot=ws+off; off+=(size_t)NB*NL;
  unsigned* sT=(unsigned*)(ws+off); off+=NB;
  off=(off+3)&~(size_t)3;
  // slab and skeys are phase-disjoint within a layer -> alias the same region
  unsigned* slab=(unsigned*)(ws+off);   // NB*NTB*SLOTS = 25.6 MB
  unsigned* skeys=(unsigned*)(ws+off);  // NB*NSUB     =  8.4 MB (aliased)
  off += (size_t)NB*NTB*SLOTS;          // total ~88 MB

  // query features; layer-0 features at stride 96
  pad_copy_k<<<(NB*96+255)/256,256,0,stream>>>(x, xq0, NB, 83, 96);
  pad_copy_k<<<((size_t)NT*96+255)/256,256,0,stream>>>(txr, tbA, NT, 83, 96);
  mlp_gemm_k<<<(NB+127)/128,256,0,stream>>>(xq0,96,3,W1,83,b1,xq1,NB);
  mlp_gemm_k<<<(NB+127)/128,256,0,stream>>>(xq1,128,4,W2,128,b2,xq2,NB);
  mlp_gemm_k<<<(NB+127)/128,256,0,stream>>>(xq2,128,4,W3,128,b3,xq3,NB);
  mlp8_k<<<(NB+31)/32,256,0,stream>>>(xq3,W4,b4,xq4,NB);
  softmax_k<<<(NB+255)/256,256,0,stream>>>(xq4,NB);
  rownorm_k<<<(NB+3)/4,256,0,stream>>>(xq0,qnb+0*NB,NB,96);
  rownorm_k<<<(NB+3)/4,256,0,stream>>>(xq1,qnb+1*NB,NB,128);
  rownorm_k<<<(NB+3)/4,256,0,stream>>>(xq2,qnb+2*NB,NB,128);
  rownorm_k<<<(NB+3)/4,256,0,stream>>>(xq3,qnb+3*NB,NB,128);
  rownorm_k<<<(NB+3)/4,256,0,stream>>>(xq4,qnb+4*NB,NB,32);

  auto knn_layer = [&](const float* Qm, const float* Bank, const float* qnl,
                       int dp, int first){
    rownorm_k<<<(NT+3)/4,256,0,stream>>>(Bank,tnb,NT,dp);
    sub_gather_k<<<(NSUB*dp+NSUB+255)/256,256,0,stream>>>(Bank,tnb,Tsub,tnsub,dp);
    dist_key_k<<<dim3(NB/QT,NSUB/TT),256,0,stream>>>(Qm,Tsub,qnl,tnsub,lbl,skeys,dp,NSUB);
    sel64_k<<<NB,256,0,stream>>>(skeys,sT);
    dist_fused2_k<<<dim3(NB/128,NTB),256,0,stream>>>(Qm,Bank,qnl,tnb,lbl,sT,slab,dp);
    final_k<<<NB,256,0,stream>>>(slab,Qm,Bank,qnl,tnb,lbl,tot,first,dp);
  };

  knn_layer(xq0, tbA, qnb+0*NB, 96, 1);
  mlp_gemm_k<<<(NT+127)/128,256,0,stream>>>(tbA,96,3,W1,83,b1,tbB,NT);
  knn_layer(xq1, tbB, qnb+1*NB, 128, 0);
  mlp_gemm_k<<<(NT+127)/128,256,0,stream>>>(tbB,128,4,W2,128,b2,tbA,NT);
  knn_layer(xq2, tbA, qnb+2*NB, 128, 0);
  mlp_gemm_k<<<(NT+127)/128,256,0,stream>>>(tbA,128,4,W3,128,b3,tbB,NT);
  knn_layer(xq3, tbB, qnb+3*NB, 128, 0);
  mlp8_k<<<(NT+31)/32,256,0,stream>>>(tbB,W4,b4,tb4,NT);
  softmax_k<<<(NT+255)/256,256,0,stream>>>(tb4,NT);
  knn_layer(xq4, tb4, qnb+4*NB, 32, 0);

  pvalue_k<<<NB,256,0,stream>>>(tot,cal,out);
}